// Round 1
// baseline (575.324 us; speedup 1.0000x reference)
//
#include <hip/hip_runtime.h>
#include <math.h>

#define BS 64
#define NOBJ 256
#define TTOK 32
#define DIM 512
#define NREL 8
#define DKK 64
#define NN 65536

typedef __attribute__((ext_vector_type(8))) short bf16x8;
typedef __attribute__((ext_vector_type(4))) float f32x4;

__device__ __forceinline__ unsigned short f2bf(float x) {
    union { float f; unsigned int u; } c; c.f = x;
    unsigned int u = c.u;
    return (unsigned short)((u + 0x7fffu + ((u >> 16) & 1u)) >> 16);
}

// ---------------- K1: text summary -> t_summary (bf16, 64x512) ----------------
__global__ void k_text(const float* __restrict__ tt, const float* __restrict__ t_mask,
                       const float* __restrict__ tc_w, const float* __restrict__ tc_b,
                       unsigned short* __restrict__ ts_bf) {
    int b = blockIdx.x;
    int tid = threadIdx.x;
    __shared__ float red[TTOK][8];
    __shared__ float sc[TTOK];
    {
        int tok = tid >> 3, seg = tid & 7;
        const float* tp = tt + (size_t)(b * TTOK + tok) * DIM + seg * 64;
        const float* wp = tc_w + seg * 64;
        float s = 0.f;
#pragma unroll
        for (int i = 0; i < 16; ++i) {
            float4 a = *(const float4*)(tp + i * 4);
            float4 w = *(const float4*)(wp + i * 4);
            s += a.x * w.x + a.y * w.y + a.z * w.z + a.w * w.w;
        }
        red[tok][seg] = s;
    }
    __syncthreads();
    if (tid < TTOK) {
        float s = 0.f;
#pragma unroll
        for (int i = 0; i < 8; ++i) s += red[tid][i];
        float m = t_mask[b * TTOK + tid];
        float tc = m * s + tc_b[0];               // dot(t*mask, w) + bias
        float sig = 1.f / (1.f + __expf(-tc));
        sc[tid] = (m != 0.f) ? m * sig : 0.f;     // weight applied to raw t
    }
    __syncthreads();
    for (int d = tid; d < DIM; d += 256) {
        float acc = 0.f;
#pragma unroll
        for (int tok = 0; tok < TTOK; ++tok)
            acc += tt[(size_t)(b * TTOK + tok) * DIM + d] * sc[tok];
        ts_bf[b * DIM + d] = f2bf(acc);
    }
}

// ---------------- K3a: convert v,b to bf16 ----------------
__global__ void k_convert(const float* __restrict__ v, const float* __restrict__ b,
                          unsigned short* __restrict__ v_bf, unsigned short* __restrict__ b_bf) {
    const float* src = blockIdx.y ? b : v;
    unsigned short* dst = blockIdx.y ? b_bf : v_bf;
    size_t i = ((size_t)blockIdx.x * 256 + threadIdx.x) * 4;
    float4 a = *(const float4*)(src + i);
    ushort4 o;
    o.x = f2bf(a.x); o.y = f2bf(a.y); o.z = f2bf(a.z); o.w = f2bf(a.w);
    *(ushort4*)(dst + i) = o;
}

// ---------------- K3b: weights -> WT (2560 cols x 512 k, bf16, k-contiguous) ----------------
__global__ void k_wt(const float* __restrict__ w0, const float* __restrict__ w1,
                     const float* __restrict__ w2, const float* __restrict__ w3,
                     const float* __restrict__ w4, unsigned short* __restrict__ WT) {
    int wsel = blockIdx.z;
    const float* W = wsel == 0 ? w0 : wsel == 1 ? w1 : wsel == 2 ? w2 : wsel == 3 ? w3 : w4;
    int k0 = blockIdx.x * 64, d0 = blockIdx.y * 64;
    __shared__ float tile[64][65];
    int tid = threadIdx.x;
#pragma unroll
    for (int p = 0; p < 16; ++p) {
        int lin = p * 256 + tid;
        int kk = lin >> 6, dd = lin & 63;
        tile[kk][dd] = W[(size_t)(k0 + kk) * DIM + d0 + dd];
    }
    __syncthreads();
    unsigned short* outp = WT + (size_t)wsel * DIM * DIM;
#pragma unroll
    for (int p = 0; p < 16; ++p) {
        int lin = p * 256 + tid;
        int dd = lin >> 6, kk = lin & 63;
        outp[(size_t)(d0 + dd) * DIM + k0 + kk] = f2bf(tile[kk][dd]);
    }
}

// ---------------- K2: tmap = relu(ts @ tmap_w + tmap_b), (64 x 65536) f32 ----------------
__launch_bounds__(256)
__global__ void k_tmap(const unsigned short* __restrict__ ts_bf,
                       const float* __restrict__ tmap_w, const float* __restrict__ tmap_b,
                       float* __restrict__ tmap) {
    int j0 = blockIdx.x * 64;
    int tid = threadIdx.x;
    int w = tid >> 6, lane = tid & 63, q = lane >> 4, li = lane & 15;
    __shared__ __align__(16) unsigned short Bt[64][40];
    f32x4 acc[4];
#pragma unroll
    for (int ct = 0; ct < 4; ++ct) acc[ct] = (f32x4){0.f, 0.f, 0.f, 0.f};

    for (int ks = 0; ks < 16; ++ks) {
        int k0 = ks * 32;
#pragma unroll
        for (int p = 0; p < 8; ++p) {
            int kk = (tid >> 6) + p * 4;
            int c = tid & 63;
            Bt[c][kk] = f2bf(tmap_w[(size_t)(k0 + kk) * NN + j0 + c]);
        }
        __syncthreads();
        bf16x8 a = *(const bf16x8*)(ts_bf + (size_t)(w * 16 + li) * DIM + k0 + q * 8);
#pragma unroll
        for (int ct = 0; ct < 4; ++ct) {
            bf16x8 bb = *(const bf16x8*)(&Bt[ct * 16 + li][q * 8]);
            acc[ct] = __builtin_amdgcn_mfma_f32_16x16x32_bf16(a, bb, acc[ct], 0, 0, 0);
        }
        __syncthreads();
    }
#pragma unroll
    for (int ct = 0; ct < 4; ++ct) {
        int j = j0 + ct * 16 + li;
        float bias = tmap_b[j];
#pragma unroll
        for (int i = 0; i < 4; ++i) {
            int bb = w * 16 + q * 4 + i;
            float val = fmaxf(acc[ct][i] + bias, 0.f);
            tmap[(size_t)bb * NN + j] = val;
        }
    }
}

// ---------------- K4: 5 projections, bf16 MFMA, 128x128 tiles ----------------
__launch_bounds__(256)
__global__ void k_proj(const unsigned short* __restrict__ v_bf, const unsigned short* __restrict__ b_bf,
                       const unsigned short* __restrict__ WT,
                       const float* __restrict__ bias0, const float* __restrict__ bias1,
                       const float* __restrict__ bias2, const float* __restrict__ bias3,
                       const float* __restrict__ bias4, const float* __restrict__ v_mask,
                       unsigned short* __restrict__ wg1, unsigned short* __restrict__ wg2,
                       unsigned short* __restrict__ wk, unsigned short* __restrict__ wq,
                       unsigned short* __restrict__ wvT) {
    int bx = blockIdx.x;          // 128 row blocks of 128
    int by = blockIdx.y;          // 20 col blocks of 128 (5 weights x 4)
    int m0 = bx * 128;
    int wsel = by >> 2;
    const unsigned short* A = (wsel < 2) ? b_bf : v_bf;
    int tid = threadIdx.x;
    int w = tid >> 6, lane = tid & 63, q = lane >> 4, li = lane & 15;
    int rh = w & 1, ch = w >> 1;
    __shared__ __align__(16) unsigned short A_lds[128][40];
    f32x4 acc[4][4];
#pragma unroll
    for (int rt = 0; rt < 4; ++rt)
#pragma unroll
        for (int ct = 0; ct < 4; ++ct) acc[rt][ct] = (f32x4){0.f, 0.f, 0.f, 0.f};

    const unsigned short* WTb = WT + (size_t)by * 128 * DIM;

    for (int ks = 0; ks < 16; ++ks) {
        int k0 = ks * 32;
        {
            int row = tid >> 1, kc = (tid & 1) * 16;
            const unsigned short* src = A + (size_t)(m0 + row) * DIM + k0 + kc;
            bf16x8 x0 = *(const bf16x8*)(src);
            bf16x8 x1 = *(const bf16x8*)(src + 8);
            *(bf16x8*)(&A_lds[row][kc]) = x0;
            *(bf16x8*)(&A_lds[row][kc + 8]) = x1;
        }
        __syncthreads();
        bf16x8 af[4], bfr[4];
#pragma unroll
        for (int rt = 0; rt < 4; ++rt)
            af[rt] = *(const bf16x8*)(&A_lds[rh * 64 + rt * 16 + li][q * 8]);
#pragma unroll
        for (int ct = 0; ct < 4; ++ct)
            bfr[ct] = *(const bf16x8*)(WTb + (size_t)(ch * 64 + ct * 16 + li) * DIM + k0 + q * 8);
#pragma unroll
        for (int rt = 0; rt < 4; ++rt)
#pragma unroll
            for (int ct = 0; ct < 4; ++ct)
                acc[rt][ct] = __builtin_amdgcn_mfma_f32_16x16x32_bf16(af[rt], bfr[ct], acc[rt][ct], 0, 0, 0);
        __syncthreads();
    }

    const float* bias = wsel == 0 ? bias0 : wsel == 1 ? bias1 : wsel == 2 ? bias2 : wsel == 3 ? bias3 : bias4;
    int dblk = (by & 3) * 128;
#pragma unroll
    for (int ct = 0; ct < 4; ++ct) {
        int d = dblk + ch * 64 + ct * 16 + li;
        float bs = bias[d];
#pragma unroll
        for (int rt = 0; rt < 4; ++rt) {
#pragma unroll
            for (int i = 0; i < 4; ++i) {
                int bn = m0 + rh * 64 + rt * 16 + q * 4 + i;
                float val = acc[rt][ct][i] + bs;
                if (wsel < 2) val *= v_mask[bn];
                unsigned short h = f2bf(val);
                if (wsel == 0)      wg1[(size_t)bn * DIM + d] = h;
                else if (wsel == 1) wg2[(size_t)bn * DIM + d] = h;
                else if (wsel == 2) wk[(size_t)bn * DIM + d] = h;
                else if (wsel == 3) wq[(size_t)bn * DIM + d] = h;
                else {
                    int bb = bn >> 8, n = bn & 255;
                    int r = d >> 6, dkc = d & 63;
                    wvT[((size_t)((bb * NREL + r) * DKK) + dkc) * NOBJ + n] = h;
                }
            }
        }
    }
}

// ---------------- K5: fused scores + softmax + PV + residual ----------------
__launch_bounds__(256)
__global__ void k_attn(const unsigned short* __restrict__ wg1, const unsigned short* __restrict__ wg2,
                       const unsigned short* __restrict__ wk, const unsigned short* __restrict__ wq,
                       const unsigned short* __restrict__ wvT,
                       const float* __restrict__ tmap, const float* __restrict__ v_mask,
                       const float* __restrict__ v, float* __restrict__ out) {
    int br = blockIdx.x;            // b*8 + r
    int nt = blockIdx.y;            // 8 row-tiles of 32
    int b = br >> 3, r = br & 7;
    int n0 = nt * 32;
    int tid = threadIdx.x;
    int w = tid >> 6, lane = tid & 63, q = lane >> 4, li = lane & 15;
    int rt = w & 1, ch = w >> 1;

    __shared__ __align__(16) unsigned short P_lds[32][264];
    __shared__ float redmax[2][32];
    __shared__ float redsum[2][32];
    __shared__ float linv[32];

    bf16x8 ag[2], ak[2];
    {
        int n = n0 + rt * 16 + li;
        const unsigned short* g1p = wg1 + (size_t)(b * NOBJ + n) * DIM + r * DKK;
        const unsigned short* kp  = wk  + (size_t)(b * NOBJ + n) * DIM + r * DKK;
#pragma unroll
        for (int ks = 0; ks < 2; ++ks) {
            ag[ks] = *(const bf16x8*)(g1p + ks * 32 + q * 8);
            ak[ks] = *(const bf16x8*)(kp + ks * 32 + q * 8);
        }
    }

    float sreg[32];
    float mloc[4] = {-INFINITY, -INFINITY, -INFINITY, -INFINITY};
#pragma unroll
    for (int j8 = 0; j8 < 8; ++j8) {
        int j = ch * 8 + j8;
        int mcol = j * 16 + li;
        const unsigned short* g2p = wg2 + (size_t)(b * NOBJ + mcol) * DIM + r * DKK;
        const unsigned short* qp  = wq  + (size_t)(b * NOBJ + mcol) * DIM + r * DKK;
        f32x4 accG = (f32x4){0.f, 0.f, 0.f, 0.f};
        f32x4 accK = (f32x4){0.f, 0.f, 0.f, 0.f};
#pragma unroll
        for (int ks = 0; ks < 2; ++ks) {
            bf16x8 bg = *(const bf16x8*)(g2p + ks * 32 + q * 8);
            accG = __builtin_amdgcn_mfma_f32_16x16x32_bf16(ag[ks], bg, accG, 0, 0, 0);
            bf16x8 bq = *(const bf16x8*)(qp + ks * 32 + q * 8);
            accK = __builtin_amdgcn_mfma_f32_16x16x32_bf16(ak[ks], bq, accK, 0, 0, 0);
        }
        float vm = v_mask[b * NOBJ + mcol];
#pragma unroll
        for (int i = 0; i < 4; ++i) {
            int n = n0 + rt * 16 + q * 4 + i;
            float tm = tmap[(size_t)b * NN + n * 256 + mcol];
            float g = fmaxf(accG[i], 0.f) + tm;
            float s = __logf(fmaxf(g, 1e-6f)) + accK[i] * 0.125f;
            if (vm == 0.f) s = -INFINITY;
            sreg[j8 * 4 + i] = s;
            mloc[i] = fmaxf(mloc[i], s);
        }
    }
#pragma unroll
    for (int i = 0; i < 4; ++i) {
        float m = mloc[i];
        m = fmaxf(m, __shfl_xor(m, 1));
        m = fmaxf(m, __shfl_xor(m, 2));
        m = fmaxf(m, __shfl_xor(m, 4));
        m = fmaxf(m, __shfl_xor(m, 8));
        mloc[i] = m;
    }
    if (li == 0) {
#pragma unroll
        for (int i = 0; i < 4; ++i) redmax[ch][rt * 16 + q * 4 + i] = mloc[i];
    }
    __syncthreads();
    float rowM[4], sloc[4];
#pragma unroll
    for (int i = 0; i < 4; ++i) {
        int row = rt * 16 + q * 4 + i;
        rowM[i] = fmaxf(redmax[0][row], redmax[1][row]);
        sloc[i] = 0.f;
    }
#pragma unroll
    for (int j8 = 0; j8 < 8; ++j8) {
        int j = ch * 8 + j8;
#pragma unroll
        for (int i = 0; i < 4; ++i) {
            float p = __expf(sreg[j8 * 4 + i] - rowM[i]);
            sloc[i] += p;
            P_lds[rt * 16 + q * 4 + i][j * 16 + li] = f2bf(p);
        }
    }
#pragma unroll
    for (int i = 0; i < 4; ++i) {
        float s = sloc[i];
        s += __shfl_xor(s, 1);
        s += __shfl_xor(s, 2);
        s += __shfl_xor(s, 4);
        s += __shfl_xor(s, 8);
        sloc[i] = s;
    }
    if (li == 0) {
#pragma unroll
        for (int i = 0; i < 4; ++i) redsum[ch][rt * 16 + q * 4 + i] = sloc[i];
    }
    __syncthreads();
    if (tid < 32) linv[tid] = 1.f / (redsum[0][tid] + redsum[1][tid]);
    __syncthreads();

    f32x4 o[2];
    o[0] = (f32x4){0.f, 0.f, 0.f, 0.f};
    o[1] = (f32x4){0.f, 0.f, 0.f, 0.f};
#pragma unroll
    for (int ks = 0; ks < 8; ++ks) {
        bf16x8 a = *(const bf16x8*)(&P_lds[rt * 16 + li][ks * 32 + q * 8]);
#pragma unroll
        for (int c2 = 0; c2 < 2; ++c2) {
            int dkc = (ch * 2 + c2) * 16 + li;
            bf16x8 bb = *(const bf16x8*)(wvT + (size_t)(br * DKK + dkc) * NOBJ + ks * 32 + q * 8);
            o[c2] = __builtin_amdgcn_mfma_f32_16x16x32_bf16(a, bb, o[c2], 0, 0, 0);
        }
    }
#pragma unroll
    for (int c2 = 0; c2 < 2; ++c2) {
        int dkc = (ch * 2 + c2) * 16 + li;
        int d = r * DKK + dkc;
#pragma unroll
        for (int i = 0; i < 4; ++i) {
            int row = rt * 16 + q * 4 + i;
            int n = n0 + row;
            size_t idx = (size_t)(b * NOBJ + n) * DIM + d;
            out[idx] = o[c2][i] * linv[row] + v[idx];
        }
    }
}

extern "C" void kernel_launch(void* const* d_in, const int* in_sizes, int n_in,
                              void* d_out, int out_size, void* d_ws, size_t ws_size,
                              hipStream_t stream) {
    const float* v      = (const float*)d_in[0];
    const float* b      = (const float*)d_in[1];
    const float* v_mask = (const float*)d_in[2];
    const float* t      = (const float*)d_in[3];
    const float* t_mask = (const float*)d_in[4];
    const float* WG1_w  = (const float*)d_in[5];
    const float* WG1_b  = (const float*)d_in[6];
    const float* WG2_w  = (const float*)d_in[7];
    const float* WG2_b  = (const float*)d_in[8];
    const float* WK_w   = (const float*)d_in[9];
    const float* WK_b   = (const float*)d_in[10];
    const float* WQ_w   = (const float*)d_in[11];
    const float* WQ_b   = (const float*)d_in[12];
    const float* WV_w   = (const float*)d_in[13];
    const float* WV_b   = (const float*)d_in[14];
    const float* tc_w   = (const float*)d_in[15];
    const float* tc_b   = (const float*)d_in[16];
    const float* tmap_w = (const float*)d_in[17];
    const float* tmap_b = (const float*)d_in[18];
    float* out = (float*)d_out;

    char* ws = (char*)d_ws;
    size_t off = 0;
    auto alloc = [&](size_t bytes) {
        void* p = ws + off;
        off += (bytes + 255) & ~(size_t)255;
        return p;
    };
    unsigned short* ts_bf = (unsigned short*)alloc((size_t)BS * DIM * 2);
    float* tmap           = (float*)alloc((size_t)BS * NN * 4);
    unsigned short* v_bf  = (unsigned short*)alloc((size_t)BS * NOBJ * DIM * 2);
    unsigned short* b_bf  = (unsigned short*)alloc((size_t)BS * NOBJ * DIM * 2);
    unsigned short* WT    = (unsigned short*)alloc((size_t)5 * DIM * DIM * 2);
    unsigned short* wg1   = (unsigned short*)alloc((size_t)BS * NOBJ * DIM * 2);
    unsigned short* wg2   = (unsigned short*)alloc((size_t)BS * NOBJ * DIM * 2);
    unsigned short* wk    = (unsigned short*)alloc((size_t)BS * NOBJ * DIM * 2);
    unsigned short* wq    = (unsigned short*)alloc((size_t)BS * NOBJ * DIM * 2);
    unsigned short* wvT   = (unsigned short*)alloc((size_t)BS * NOBJ * DIM * 2);

    k_text<<<dim3(BS), dim3(256), 0, stream>>>(t, t_mask, tc_w, tc_b, ts_bf);
    k_convert<<<dim3(8192, 2), dim3(256), 0, stream>>>(v, b, v_bf, b_bf);
    k_wt<<<dim3(8, 8, 5), dim3(256), 0, stream>>>(WG1_w, WG2_w, WK_w, WQ_w, WV_w, WT);
    k_tmap<<<dim3(1024), dim3(256), 0, stream>>>(ts_bf, tmap_w, tmap_b, tmap);
    k_proj<<<dim3(128, 20), dim3(256), 0, stream>>>(v_bf, b_bf, WT,
                                                    WG1_b, WG2_b, WK_b, WQ_b, WV_b, v_mask,
                                                    wg1, wg2, wk, wq, wvT);
    k_attn<<<dim3(512, 8), dim3(256), 0, stream>>>(wg1, wg2, wk, wq, wvT, tmap, v_mask, v, out);
}

// Round 2
// 499.835 us; speedup vs baseline: 1.1510x; 1.1510x over previous
//
#include <hip/hip_runtime.h>
#include <math.h>

#define BS 64
#define NOBJ 256
#define TTOK 32
#define DIM 512
#define NREL 8
#define DKK 64
#define NN 65536

typedef __attribute__((ext_vector_type(8))) short bf16x8;
typedef __attribute__((ext_vector_type(4))) float f32x4;

__device__ __forceinline__ unsigned short f2bf(float x) {
    union { float f; unsigned int u; } c; c.f = x;
    unsigned int u = c.u;
    return (unsigned short)((u + 0x7fffu + ((u >> 16) & 1u)) >> 16);
}
__device__ __forceinline__ float bf2f(unsigned short h) {
    union { unsigned int u; float f; } c; c.u = ((unsigned int)h) << 16;
    return c.f;
}
// async 16B global -> LDS (wave-uniform LDS base + lane*16)
__device__ __forceinline__ void gl2lds16(const unsigned short* g, unsigned short* l) {
    __builtin_amdgcn_global_load_lds((const __attribute__((address_space(1))) void*)g,
                                     (__attribute__((address_space(3))) void*)l, 16, 0, 0);
}

// ---------------- K1: text summary -> t_summary (bf16, 64x512) ----------------
__global__ void k_text(const float* __restrict__ tt, const float* __restrict__ t_mask,
                       const float* __restrict__ tc_w, const float* __restrict__ tc_b,
                       unsigned short* __restrict__ ts_bf) {
    int b = blockIdx.x;
    int tid = threadIdx.x;
    __shared__ float red[TTOK][8];
    __shared__ float sc[TTOK];
    {
        int tok = tid >> 3, seg = tid & 7;
        const float* tp = tt + (size_t)(b * TTOK + tok) * DIM + seg * 64;
        const float* wp = tc_w + seg * 64;
        float s = 0.f;
#pragma unroll
        for (int i = 0; i < 16; ++i) {
            float4 a = *(const float4*)(tp + i * 4);
            float4 w = *(const float4*)(wp + i * 4);
            s += a.x * w.x + a.y * w.y + a.z * w.z + a.w * w.w;
        }
        red[tok][seg] = s;
    }
    __syncthreads();
    if (tid < TTOK) {
        float s = 0.f;
#pragma unroll
        for (int i = 0; i < 8; ++i) s += red[tid][i];
        float m = t_mask[b * TTOK + tid];
        float tc = m * s + tc_b[0];
        float sig = 1.f / (1.f + __expf(-tc));
        sc[tid] = (m != 0.f) ? m * sig : 0.f;
    }
    __syncthreads();
    for (int d = tid; d < DIM; d += 256) {
        float acc = 0.f;
#pragma unroll
        for (int tok = 0; tok < TTOK; ++tok)
            acc += tt[(size_t)(b * TTOK + tok) * DIM + d] * sc[tok];
        ts_bf[b * DIM + d] = f2bf(acc);
    }
}

// ---------------- K3a: convert v,b to bf16 ----------------
__global__ void k_convert(const float* __restrict__ v, const float* __restrict__ b,
                          unsigned short* __restrict__ v_bf, unsigned short* __restrict__ b_bf) {
    const float* src = blockIdx.y ? b : v;
    unsigned short* dst = blockIdx.y ? b_bf : v_bf;
    size_t i = ((size_t)blockIdx.x * 256 + threadIdx.x) * 4;
    float4 a = *(const float4*)(src + i);
    ushort4 o;
    o.x = f2bf(a.x); o.y = f2bf(a.y); o.z = f2bf(a.z); o.w = f2bf(a.w);
    *(ushort4*)(dst + i) = o;
}

// ---------------- K3b: weights -> WT (2560 cols x 512 k, bf16, k-contiguous) ----------------
__global__ void k_wt(const float* __restrict__ w0, const float* __restrict__ w1,
                     const float* __restrict__ w2, const float* __restrict__ w3,
                     const float* __restrict__ w4, unsigned short* __restrict__ WT) {
    int wsel = blockIdx.z;
    const float* W = wsel == 0 ? w0 : wsel == 1 ? w1 : wsel == 2 ? w2 : wsel == 3 ? w3 : w4;
    int k0 = blockIdx.x * 64, d0 = blockIdx.y * 64;
    __shared__ float tile[64][65];
    int tid = threadIdx.x;
#pragma unroll
    for (int p = 0; p < 16; ++p) {
        int lin = p * 256 + tid;
        int kk = lin >> 6, dd = lin & 63;
        tile[kk][dd] = W[(size_t)(k0 + kk) * DIM + d0 + dd];
    }
    __syncthreads();
    unsigned short* outp = WT + (size_t)wsel * DIM * DIM;
#pragma unroll
    for (int p = 0; p < 16; ++p) {
        int lin = p * 256 + tid;
        int dd = lin >> 6, kk = lin & 63;
        outp[(size_t)(d0 + dd) * DIM + k0 + kk] = f2bf(tile[kk][dd]);
    }
}

// ---------------- K2: tmap = relu(ts @ tmap_w + tmap_b), (64 x 65536) -> bf16 ----------------
__launch_bounds__(256)
__global__ void k_tmap(const unsigned short* __restrict__ ts_bf,
                       const float* __restrict__ tmap_w, const float* __restrict__ tmap_b,
                       unsigned short* __restrict__ tmap) {
    int j0 = blockIdx.x * 64;
    int tid = threadIdx.x;
    int w = tid >> 6, lane = tid & 63, q = lane >> 4, li = lane & 15;
    __shared__ __align__(16) unsigned short Bt[64][40];
    f32x4 acc[4];
#pragma unroll
    for (int ct = 0; ct < 4; ++ct) acc[ct] = (f32x4){0.f, 0.f, 0.f, 0.f};

    for (int ks = 0; ks < 16; ++ks) {
        int k0 = ks * 32;
#pragma unroll
        for (int p = 0; p < 8; ++p) {
            int kk = (tid >> 6) + p * 4;
            int c = tid & 63;
            Bt[c][kk] = f2bf(tmap_w[(size_t)(k0 + kk) * NN + j0 + c]);
        }
        __syncthreads();
        bf16x8 a = *(const bf16x8*)(ts_bf + (size_t)(w * 16 + li) * DIM + k0 + q * 8);
#pragma unroll
        for (int ct = 0; ct < 4; ++ct) {
            bf16x8 bb = *(const bf16x8*)(&Bt[ct * 16 + li][q * 8]);
            acc[ct] = __builtin_amdgcn_mfma_f32_16x16x32_bf16(a, bb, acc[ct], 0, 0, 0);
        }
        __syncthreads();
    }
#pragma unroll
    for (int ct = 0; ct < 4; ++ct) {
        int j = j0 + ct * 16 + li;
        float bias = tmap_b[j];
#pragma unroll
        for (int i = 0; i < 4; ++i) {
            int bb = w * 16 + q * 4 + i;
            float val = fmaxf(acc[ct][i] + bias, 0.f);
            tmap[(size_t)bb * NN + j] = f2bf(val);
        }
    }
}

// ---------------- K4: 5 projections, m97-style: global_load_lds staging for A and B ----------------
// LDS tile layout (A and B identical): 128 rows x 32 k, unpadded 64 B/row, with XOR
// segment swizzle: logical 16B segment q of row r lives at physical segment
// q ^ (((r & 15) >> 1) & 3). Staging lane l covers row chunk*16 + (l>>2), phys seg l&3,
// so it fetches logical seg (l&3) ^ ((l>>3)&3). Fragment reads (row = base16+li, seg q)
// then hit 8 distinct 4-bank groups x 2 lanes -> conflict-free b128.
__launch_bounds__(256)
__global__ void k_proj(const unsigned short* __restrict__ v_bf, const unsigned short* __restrict__ b_bf,
                       const unsigned short* __restrict__ WT,
                       const float* __restrict__ bias0, const float* __restrict__ bias1,
                       const float* __restrict__ bias2, const float* __restrict__ bias3,
                       const float* __restrict__ bias4, const float* __restrict__ v_mask,
                       unsigned short* __restrict__ wg1, unsigned short* __restrict__ wg2,
                       unsigned short* __restrict__ wk, unsigned short* __restrict__ wq,
                       unsigned short* __restrict__ wvT) {
    int bx = blockIdx.x;          // 128 row blocks of 128
    int by = blockIdx.y;          // 20 col blocks of 128 (5 weights x 4)
    int m0 = bx * 128;
    int wsel = by >> 2;
    const unsigned short* A = (wsel < 2) ? b_bf : v_bf;
    int tid = threadIdx.x;
    int w = tid >> 6, lane = tid & 63, q = lane >> 4, li = lane & 15;
    int rh = w & 1, ch = w >> 1;

    // smem: [As 4096][Bs 4096] shorts for K-loop; reused as T[128][136] for wvT transpose
    __shared__ __align__(16) unsigned short smem[128 * 136];
    unsigned short* As = smem;
    unsigned short* Bs = smem + 4096;

    f32x4 acc[4][4];
#pragma unroll
    for (int rt = 0; rt < 4; ++rt)
#pragma unroll
        for (int ct = 0; ct < 4; ++ct) acc[rt][ct] = (f32x4){0.f, 0.f, 0.f, 0.f};

    const unsigned short* WTb = WT + (size_t)by * 128 * DIM;

    // staging addresses (hoisted): wave w covers chunks {w, w+4}; chunk = 16 rows
    int rho = lane >> 2;                               // row within chunk
    int qs = (lane & 3) ^ ((lane >> 3) & 3);           // swizzled logical segment to fetch
    int rA0 = w * 16 + rho, rA1 = (w + 4) * 16 + rho;  // tile rows
    const unsigned short* Ag0 = A + (size_t)(m0 + rA0) * DIM + qs * 8;
    const unsigned short* Ag1 = A + (size_t)(m0 + rA1) * DIM + qs * 8;
    const unsigned short* Bg0 = WTb + (size_t)rA0 * DIM + qs * 8;
    const unsigned short* Bg1 = WTb + (size_t)rA1 * DIM + qs * 8;
    unsigned short* Al0 = As + w * 512;        // chunk w     (wave-uniform)
    unsigned short* Al1 = As + (w + 4) * 512;  // chunk w+4
    unsigned short* Bl0 = Bs + w * 512;
    unsigned short* Bl1 = Bs + (w + 4) * 512;

    int sseg = (q ^ ((li >> 1) & 3)) * 8;  // swizzled segment offset for fragment reads

    for (int ks = 0; ks < 16; ++ks) {
        int k0 = ks * 32;
        gl2lds16(Ag0 + k0, Al0);
        gl2lds16(Ag1 + k0, Al1);
        gl2lds16(Bg0 + k0, Bl0);
        gl2lds16(Bg1 + k0, Bl1);
        __syncthreads();
        bf16x8 af[4], bfr[4];
#pragma unroll
        for (int rt = 0; rt < 4; ++rt)
            af[rt] = *(const bf16x8*)(As + (rh * 64 + rt * 16 + li) * 32 + sseg);
#pragma unroll
        for (int ct = 0; ct < 4; ++ct)
            bfr[ct] = *(const bf16x8*)(Bs + (ch * 64 + ct * 16 + li) * 32 + sseg);
#pragma unroll
        for (int rt = 0; rt < 4; ++rt)
#pragma unroll
            for (int ct = 0; ct < 4; ++ct)
                acc[rt][ct] = __builtin_amdgcn_mfma_f32_16x16x32_bf16(af[rt], bfr[ct], acc[rt][ct], 0, 0, 0);
        __syncthreads();
    }

    const float* bias = wsel == 0 ? bias0 : wsel == 1 ? bias1 : wsel == 2 ? bias2 : wsel == 3 ? bias3 : bias4;
    int dblk = (by & 3) * 128;

    if (wsel < 4) {
#pragma unroll
        for (int ct = 0; ct < 4; ++ct) {
            int d = dblk + ch * 64 + ct * 16 + li;
            float bs = bias[d];
#pragma unroll
            for (int rt = 0; rt < 4; ++rt) {
#pragma unroll
                for (int i = 0; i < 4; ++i) {
                    int bn = m0 + rh * 64 + rt * 16 + q * 4 + i;
                    float val = acc[rt][ct][i] + bs;
                    if (wsel < 2) val *= v_mask[bn];
                    unsigned short h = f2bf(val);
                    if (wsel == 0)      wg1[(size_t)bn * DIM + d] = h;
                    else if (wsel == 1) wg2[(size_t)bn * DIM + d] = h;
                    else if (wsel == 2) wk[(size_t)bn * DIM + d] = h;
                    else                wq[(size_t)bn * DIM + d] = h;
                }
            }
        }
    } else {
        // transpose 128x128 tile through LDS, store wvT [(b*8+r)*64+dk][n] n-contiguous
        unsigned short (*T)[136] = (unsigned short (*)[136])smem;
#pragma unroll
        for (int ct = 0; ct < 4; ++ct) {
            int d_local = ch * 64 + ct * 16 + li;
            float bs = bias[dblk + d_local];
#pragma unroll
            for (int rt = 0; rt < 4; ++rt) {
#pragma unroll
                for (int i = 0; i < 4; ++i) {
                    int n_local = rh * 64 + rt * 16 + q * 4 + i;
                    T[d_local][n_local] = f2bf(acc[rt][ct][i] + bs);
                }
            }
        }
        __syncthreads();
        int b = m0 >> 8, nbase = m0 & 255;
        int dl = tid >> 1;
        int nh = (tid & 1) * 64;
        int d = dblk + dl;
        int rr = d >> 6, dk = d & 63;
        unsigned short* dst = wvT + ((size_t)(b * NREL + rr) * DKK + dk) * NOBJ + nbase + nh;
#pragma unroll
        for (int k = 0; k < 8; ++k)
            *(bf16x8*)(dst + k * 8) = *(const bf16x8*)(&T[dl][nh + k * 8]);
    }
}

// ---------------- K5: fused scores + softmax + PV + residual ----------------
__launch_bounds__(256)
__global__ void k_attn(const unsigned short* __restrict__ wg1, const unsigned short* __restrict__ wg2,
                       const unsigned short* __restrict__ wk, const unsigned short* __restrict__ wq,
                       const unsigned short* __restrict__ wvT,
                       const unsigned short* __restrict__ tmap, const float* __restrict__ v_mask,
                       const float* __restrict__ v, float* __restrict__ out) {
    int br = blockIdx.x;            // b*8 + r
    int nt = blockIdx.y;            // 8 row-tiles of 32
    int b = br >> 3, r = br & 7;
    int n0 = nt * 32;
    int tid = threadIdx.x;
    int w = tid >> 6, lane = tid & 63, q = lane >> 4, li = lane & 15;
    int rt = w & 1, ch = w >> 1;

    __shared__ __align__(16) unsigned short P_lds[32][264];
    __shared__ float redmax[2][32];
    __shared__ float redsum[2][32];
    __shared__ float linv[32];

    bf16x8 ag[2], ak[2];
    {
        int n = n0 + rt * 16 + li;
        const unsigned short* g1p = wg1 + (size_t)(b * NOBJ + n) * DIM + r * DKK;
        const unsigned short* kp  = wk  + (size_t)(b * NOBJ + n) * DIM + r * DKK;
#pragma unroll
        for (int ks = 0; ks < 2; ++ks) {
            ag[ks] = *(const bf16x8*)(g1p + ks * 32 + q * 8);
            ak[ks] = *(const bf16x8*)(kp + ks * 32 + q * 8);
        }
    }

    float sreg[32];
    float mloc[4] = {-INFINITY, -INFINITY, -INFINITY, -INFINITY};
#pragma unroll
    for (int j8 = 0; j8 < 8; ++j8) {
        int j = ch * 8 + j8;
        int mcol = j * 16 + li;
        const unsigned short* g2p = wg2 + (size_t)(b * NOBJ + mcol) * DIM + r * DKK;
        const unsigned short* qp  = wq  + (size_t)(b * NOBJ + mcol) * DIM + r * DKK;
        f32x4 accG = (f32x4){0.f, 0.f, 0.f, 0.f};
        f32x4 accK = (f32x4){0.f, 0.f, 0.f, 0.f};
#pragma unroll
        for (int ks = 0; ks < 2; ++ks) {
            bf16x8 bg = *(const bf16x8*)(g2p + ks * 32 + q * 8);
            accG = __builtin_amdgcn_mfma_f32_16x16x32_bf16(ag[ks], bg, accG, 0, 0, 0);
            bf16x8 bq = *(const bf16x8*)(qp + ks * 32 + q * 8);
            accK = __builtin_amdgcn_mfma_f32_16x16x32_bf16(ak[ks], bq, accK, 0, 0, 0);
        }
        float vm = v_mask[b * NOBJ + mcol];
#pragma unroll
        for (int i = 0; i < 4; ++i) {
            int n = n0 + rt * 16 + q * 4 + i;
            float tm = bf2f(tmap[(size_t)b * NN + n * 256 + mcol]);
            float g = fmaxf(accG[i], 0.f) + tm;
            float s = __logf(fmaxf(g, 1e-6f)) + accK[i] * 0.125f;
            if (vm == 0.f) s = -INFINITY;
            sreg[j8 * 4 + i] = s;
            mloc[i] = fmaxf(mloc[i], s);
        }
    }
#pragma unroll
    for (int i = 0; i < 4; ++i) {
        float m = mloc[i];
        m = fmaxf(m, __shfl_xor(m, 1));
        m = fmaxf(m, __shfl_xor(m, 2));
        m = fmaxf(m, __shfl_xor(m, 4));
        m = fmaxf(m, __shfl_xor(m, 8));
        mloc[i] = m;
    }
    if (li == 0) {
#pragma unroll
        for (int i = 0; i < 4; ++i) redmax[ch][rt * 16 + q * 4 + i] = mloc[i];
    }
    __syncthreads();
    float rowM[4], sloc[4];
#pragma unroll
    for (int i = 0; i < 4; ++i) {
        int row = rt * 16 + q * 4 + i;
        rowM[i] = fmaxf(redmax[0][row], redmax[1][row]);
        sloc[i] = 0.f;
    }
#pragma unroll
    for (int j8 = 0; j8 < 8; ++j8) {
        int j = ch * 8 + j8;
#pragma unroll
        for (int i = 0; i < 4; ++i) {
            float p = __expf(sreg[j8 * 4 + i] - rowM[i]);
            sloc[i] += p;
            P_lds[rt * 16 + q * 4 + i][j * 16 + li] = f2bf(p);
        }
    }
#pragma unroll
    for (int i = 0; i < 4; ++i) {
        float s = sloc[i];
        s += __shfl_xor(s, 1);
        s += __shfl_xor(s, 2);
        s += __shfl_xor(s, 4);
        s += __shfl_xor(s, 8);
        sloc[i] = s;
    }
    if (li == 0) {
#pragma unroll
        for (int i = 0; i < 4; ++i) redsum[ch][rt * 16 + q * 4 + i] = sloc[i];
    }
    __syncthreads();
    if (tid < 32) linv[tid] = 1.f / (redsum[0][tid] + redsum[1][tid]);
    __syncthreads();

    f32x4 o[2];
    o[0] = (f32x4){0.f, 0.f, 0.f, 0.f};
    o[1] = (f32x4){0.f, 0.f, 0.f, 0.f};
#pragma unroll
    for (int ks = 0; ks < 8; ++ks) {
        bf16x8 a = *(const bf16x8*)(&P_lds[rt * 16 + li][ks * 32 + q * 8]);
#pragma unroll
        for (int c2 = 0; c2 < 2; ++c2) {
            int dkc = (ch * 2 + c2) * 16 + li;
            bf16x8 bb = *(const bf16x8*)(wvT + (size_t)(br * DKK + dkc) * NOBJ + ks * 32 + q * 8);
            o[c2] = __builtin_amdgcn_mfma_f32_16x16x32_bf16(a, bb, o[c2], 0, 0, 0);
        }
    }
#pragma unroll
    for (int c2 = 0; c2 < 2; ++c2) {
        int dkc = (ch * 2 + c2) * 16 + li;
        int d = r * DKK + dkc;
#pragma unroll
        for (int i = 0; i < 4; ++i) {
            int row = rt * 16 + q * 4 + i;
            int n = n0 + row;
            size_t idx = (size_t)(b * NOBJ + n) * DIM + d;
            out[idx] = o[c2][i] * linv[row] + v[idx];
        }
    }
}

extern "C" void kernel_launch(void* const* d_in, const int* in_sizes, int n_in,
                              void* d_out, int out_size, void* d_ws, size_t ws_size,
                              hipStream_t stream) {
    const float* v      = (const float*)d_in[0];
    const float* b      = (const float*)d_in[1];
    const float* v_mask = (const float*)d_in[2];
    const float* t      = (const float*)d_in[3];
    const float* t_mask = (const float*)d_in[4];
    const float* WG1_w  = (const float*)d_in[5];
    const float* WG1_b  = (const float*)d_in[6];
    const float* WG2_w  = (const float*)d_in[7];
    const float* WG2_b  = (const float*)d_in[8];
    const float* WK_w   = (const float*)d_in[9];
    const float* WK_b   = (const float*)d_in[10];
    const float* WQ_w   = (const float*)d_in[11];
    const float* WQ_b   = (const float*)d_in[12];
    const float* WV_w   = (const float*)d_in[13];
    const float* WV_b   = (const float*)d_in[14];
    const float* tc_w   = (const float*)d_in[15];
    const float* tc_b   = (const float*)d_in[16];
    const float* tmap_w = (const float*)d_in[17];
    const float* tmap_b = (const float*)d_in[18];
    float* out = (float*)d_out;

    char* ws = (char*)d_ws;
    size_t off = 0;
    auto alloc = [&](size_t bytes) {
        void* p = ws + off;
        off += (bytes + 255) & ~(size_t)255;
        return p;
    };
    unsigned short* ts_bf = (unsigned short*)alloc((size_t)BS * DIM * 2);
    unsigned short* tmap  = (unsigned short*)alloc((size_t)BS * NN * 2);
    unsigned short* v_bf  = (unsigned short*)alloc((size_t)BS * NOBJ * DIM * 2);
    unsigned short* b_bf  = (unsigned short*)alloc((size_t)BS * NOBJ * DIM * 2);
    unsigned short* WT    = (unsigned short*)alloc((size_t)5 * DIM * DIM * 2);
    unsigned short* wg1   = (unsigned short*)alloc((size_t)BS * NOBJ * DIM * 2);
    unsigned short* wg2   = (unsigned short*)alloc((size_t)BS * NOBJ * DIM * 2);
    unsigned short* wk    = (unsigned short*)alloc((size_t)BS * NOBJ * DIM * 2);
    unsigned short* wq    = (unsigned short*)alloc((size_t)BS * NOBJ * DIM * 2);
    unsigned short* wvT   = (unsigned short*)alloc((size_t)BS * NOBJ * DIM * 2);

    k_text<<<dim3(BS), dim3(256), 0, stream>>>(t, t_mask, tc_w, tc_b, ts_bf);
    k_convert<<<dim3(8192, 2), dim3(256), 0, stream>>>(v, b, v_bf, b_bf);
    k_wt<<<dim3(8, 8, 5), dim3(256), 0, stream>>>(WG1_w, WG2_w, WK_w, WQ_w, WV_w, WT);
    k_tmap<<<dim3(1024), dim3(256), 0, stream>>>(ts_bf, tmap_w, tmap_b, tmap);
    k_proj<<<dim3(128, 20), dim3(256), 0, stream>>>(v_bf, b_bf, WT,
                                                    WG1_b, WG2_b, WK_b, WQ_b, WV_b, v_mask,
                                                    wg1, wg2, wk, wq, wvT);
    k_attn<<<dim3(512, 8), dim3(256), 0, stream>>>(wg1, wg2, wk, wq, wvT, tmap, v_mask, v, out);
}

// Round 3
// 494.425 us; speedup vs baseline: 1.1636x; 1.0109x over previous
//
#include <hip/hip_runtime.h>
#include <math.h>

#define BS 64
#define NOBJ 256
#define TTOK 32
#define DIM 512
#define NREL 8
#define DKK 64
#define NN 65536

typedef __attribute__((ext_vector_type(8))) short bf16x8;
typedef __attribute__((ext_vector_type(4))) float f32x4;

__device__ __forceinline__ unsigned short f2bf(float x) {
    union { float f; unsigned int u; } c; c.f = x;
    unsigned int u = c.u;
    return (unsigned short)((u + 0x7fffu + ((u >> 16) & 1u)) >> 16);
}
__device__ __forceinline__ float bf2f(unsigned short h) {
    union { unsigned int u; float f; } c; c.u = ((unsigned int)h) << 16;
    return c.f;
}
// async 16B global -> LDS (wave-uniform LDS base + lane*16)
__device__ __forceinline__ void gl2lds16(const unsigned short* g, unsigned short* l) {
    __builtin_amdgcn_global_load_lds((const __attribute__((address_space(1))) void*)g,
                                     (__attribute__((address_space(3))) void*)l, 16, 0, 0);
}

// ---------------- K1: text summary -> t_summary (bf16, 64x512) ----------------
__global__ void k_text(const float* __restrict__ tt, const float* __restrict__ t_mask,
                       const float* __restrict__ tc_w, const float* __restrict__ tc_b,
                       unsigned short* __restrict__ ts_bf) {
    int b = blockIdx.x;
    int tid = threadIdx.x;
    __shared__ float red[TTOK][8];
    __shared__ float sc[TTOK];
    {
        int tok = tid >> 3, seg = tid & 7;
        const float* tp = tt + (size_t)(b * TTOK + tok) * DIM + seg * 64;
        const float* wp = tc_w + seg * 64;
        float s = 0.f;
#pragma unroll
        for (int i = 0; i < 16; ++i) {
            float4 a = *(const float4*)(tp + i * 4);
            float4 w = *(const float4*)(wp + i * 4);
            s += a.x * w.x + a.y * w.y + a.z * w.z + a.w * w.w;
        }
        red[tok][seg] = s;
    }
    __syncthreads();
    if (tid < TTOK) {
        float s = 0.f;
#pragma unroll
        for (int i = 0; i < 8; ++i) s += red[tid][i];
        float m = t_mask[b * TTOK + tid];
        float tc = m * s + tc_b[0];
        float sig = 1.f / (1.f + __expf(-tc));
        sc[tid] = (m != 0.f) ? m * sig : 0.f;
    }
    __syncthreads();
    for (int d = tid; d < DIM; d += 256) {
        float acc = 0.f;
#pragma unroll
        for (int tok = 0; tok < TTOK; ++tok)
            acc += tt[(size_t)(b * TTOK + tok) * DIM + d] * sc[tok];
        ts_bf[b * DIM + d] = f2bf(acc);
    }
}

// ---------------- K3a: convert v,b to bf16 ----------------
__global__ void k_convert(const float* __restrict__ v, const float* __restrict__ b,
                          unsigned short* __restrict__ v_bf, unsigned short* __restrict__ b_bf) {
    const float* src = blockIdx.y ? b : v;
    unsigned short* dst = blockIdx.y ? b_bf : v_bf;
    size_t i = ((size_t)blockIdx.x * 256 + threadIdx.x) * 4;
    float4 a = *(const float4*)(src + i);
    ushort4 o;
    o.x = f2bf(a.x); o.y = f2bf(a.y); o.z = f2bf(a.z); o.w = f2bf(a.w);
    *(ushort4*)(dst + i) = o;
}

// ---------------- K3b: weights -> WT (2560 cols x 512 k, bf16, k-contiguous) ----------------
__global__ void k_wt(const float* __restrict__ w0, const float* __restrict__ w1,
                     const float* __restrict__ w2, const float* __restrict__ w3,
                     const float* __restrict__ w4, unsigned short* __restrict__ WT) {
    int wsel = blockIdx.z;
    const float* W = wsel == 0 ? w0 : wsel == 1 ? w1 : wsel == 2 ? w2 : wsel == 3 ? w3 : w4;
    int k0 = blockIdx.x * 64, d0 = blockIdx.y * 64;
    __shared__ float tile[64][65];
    int tid = threadIdx.x;
#pragma unroll
    for (int p = 0; p < 16; ++p) {
        int lin = p * 256 + tid;
        int kk = lin >> 6, dd = lin & 63;
        tile[kk][dd] = W[(size_t)(k0 + kk) * DIM + d0 + dd];
    }
    __syncthreads();
    unsigned short* outp = WT + (size_t)wsel * DIM * DIM;
#pragma unroll
    for (int p = 0; p < 16; ++p) {
        int lin = p * 256 + tid;
        int dd = lin >> 6, kk = lin & 63;
        outp[(size_t)(d0 + dd) * DIM + k0 + kk] = f2bf(tile[kk][dd]);
    }
}

// ---------------- K2: tmap = relu(ts @ tmap_w + tmap_b) -> bf16, no-LDS direct ----------------
// one wave per block, 64 cols; B-fragments built from 8 strided f32 loads
// (coalesced across the 16 lanes); A reloaded from L2-hot ts_bf (64 KB).
__launch_bounds__(64)
__global__ void k_tmap(const unsigned short* __restrict__ ts_bf,
                       const float* __restrict__ tmap_w, const float* __restrict__ tmap_b,
                       unsigned short* __restrict__ tmap) {
    int col0 = blockIdx.x * 64;
    int lane = threadIdx.x;
    int q = lane >> 4, li = lane & 15;
    f32x4 acc[4][4];
#pragma unroll
    for (int rt = 0; rt < 4; ++rt)
#pragma unroll
        for (int ct = 0; ct < 4; ++ct) acc[rt][ct] = (f32x4){0.f, 0.f, 0.f, 0.f};

    for (int kt = 0; kt < 16; ++kt) {
        int k0 = kt * 32;
        bf16x8 a[4];
#pragma unroll
        for (int rt = 0; rt < 4; ++rt)
            a[rt] = *(const bf16x8*)(ts_bf + (size_t)(rt * 16 + li) * DIM + k0 + q * 8);
#pragma unroll
        for (int ct = 0; ct < 4; ++ct) {
            const float* wp = tmap_w + (size_t)(k0 + q * 8) * NN + col0 + ct * 16 + li;
            bf16x8 bb;
#pragma unroll
            for (int j = 0; j < 8; ++j)
                bb[j] = (short)f2bf(wp[(size_t)j * NN]);
#pragma unroll
            for (int rt = 0; rt < 4; ++rt)
                acc[rt][ct] = __builtin_amdgcn_mfma_f32_16x16x32_bf16(a[rt], bb, acc[rt][ct], 0, 0, 0);
        }
    }
#pragma unroll
    for (int ct = 0; ct < 4; ++ct) {
        int j = col0 + ct * 16 + li;
        float bias = tmap_b[j];
#pragma unroll
        for (int rt = 0; rt < 4; ++rt) {
#pragma unroll
            for (int i = 0; i < 4; ++i) {
                int bb = rt * 16 + q * 4 + i;
                float val = fmaxf(acc[rt][ct][i] + bias, 0.f);
                tmap[(size_t)bb * NN + j] = f2bf(val);
            }
        }
    }
}

// ---------------- K4: 5 projections, m97-style staging (unchanged from R2) ----------------
__launch_bounds__(256)
__global__ void k_proj(const unsigned short* __restrict__ v_bf, const unsigned short* __restrict__ b_bf,
                       const unsigned short* __restrict__ WT,
                       const float* __restrict__ bias0, const float* __restrict__ bias1,
                       const float* __restrict__ bias2, const float* __restrict__ bias3,
                       const float* __restrict__ bias4, const float* __restrict__ v_mask,
                       unsigned short* __restrict__ wg1, unsigned short* __restrict__ wg2,
                       unsigned short* __restrict__ wk, unsigned short* __restrict__ wq,
                       unsigned short* __restrict__ wvT) {
    int bx = blockIdx.x;
    int by = blockIdx.y;
    int m0 = bx * 128;
    int wsel = by >> 2;
    const unsigned short* A = (wsel < 2) ? b_bf : v_bf;
    int tid = threadIdx.x;
    int w = tid >> 6, lane = tid & 63, q = lane >> 4, li = lane & 15;
    int rh = w & 1, ch = w >> 1;

    __shared__ __align__(16) unsigned short smem[128 * 136];
    unsigned short* As = smem;
    unsigned short* Bs = smem + 4096;

    f32x4 acc[4][4];
#pragma unroll
    for (int rt = 0; rt < 4; ++rt)
#pragma unroll
        for (int ct = 0; ct < 4; ++ct) acc[rt][ct] = (f32x4){0.f, 0.f, 0.f, 0.f};

    const unsigned short* WTb = WT + (size_t)by * 128 * DIM;

    int rho = lane >> 2;
    int qs = (lane & 3) ^ ((lane >> 3) & 3);
    int rA0 = w * 16 + rho, rA1 = (w + 4) * 16 + rho;
    const unsigned short* Ag0 = A + (size_t)(m0 + rA0) * DIM + qs * 8;
    const unsigned short* Ag1 = A + (size_t)(m0 + rA1) * DIM + qs * 8;
    const unsigned short* Bg0 = WTb + (size_t)rA0 * DIM + qs * 8;
    const unsigned short* Bg1 = WTb + (size_t)rA1 * DIM + qs * 8;
    unsigned short* Al0 = As + w * 512;
    unsigned short* Al1 = As + (w + 4) * 512;
    unsigned short* Bl0 = Bs + w * 512;
    unsigned short* Bl1 = Bs + (w + 4) * 512;

    int sseg = (q ^ ((li >> 1) & 3)) * 8;

    for (int ks = 0; ks < 16; ++ks) {
        int k0 = ks * 32;
        gl2lds16(Ag0 + k0, Al0);
        gl2lds16(Ag1 + k0, Al1);
        gl2lds16(Bg0 + k0, Bl0);
        gl2lds16(Bg1 + k0, Bl1);
        __syncthreads();
        bf16x8 af[4], bfr[4];
#pragma unroll
        for (int rt = 0; rt < 4; ++rt)
            af[rt] = *(const bf16x8*)(As + (rh * 64 + rt * 16 + li) * 32 + sseg);
#pragma unroll
        for (int ct = 0; ct < 4; ++ct)
            bfr[ct] = *(const bf16x8*)(Bs + (ch * 64 + ct * 16 + li) * 32 + sseg);
#pragma unroll
        for (int rt = 0; rt < 4; ++rt)
#pragma unroll
            for (int ct = 0; ct < 4; ++ct)
                acc[rt][ct] = __builtin_amdgcn_mfma_f32_16x16x32_bf16(af[rt], bfr[ct], acc[rt][ct], 0, 0, 0);
        __syncthreads();
    }

    const float* bias = wsel == 0 ? bias0 : wsel == 1 ? bias1 : wsel == 2 ? bias2 : wsel == 3 ? bias3 : bias4;
    int dblk = (by & 3) * 128;

    if (wsel < 4) {
#pragma unroll
        for (int ct = 0; ct < 4; ++ct) {
            int d = dblk + ch * 64 + ct * 16 + li;
            float bs = bias[d];
#pragma unroll
            for (int rt = 0; rt < 4; ++rt) {
#pragma unroll
                for (int i = 0; i < 4; ++i) {
                    int bn = m0 + rh * 64 + rt * 16 + q * 4 + i;
                    float val = acc[rt][ct][i] + bs;
                    if (wsel < 2) val *= v_mask[bn];
                    unsigned short h = f2bf(val);
                    if (wsel == 0)      wg1[(size_t)bn * DIM + d] = h;
                    else if (wsel == 1) wg2[(size_t)bn * DIM + d] = h;
                    else if (wsel == 2) wk[(size_t)bn * DIM + d] = h;
                    else                wq[(size_t)bn * DIM + d] = h;
                }
            }
        }
    } else {
        unsigned short (*T)[136] = (unsigned short (*)[136])smem;
#pragma unroll
        for (int ct = 0; ct < 4; ++ct) {
            int d_local = ch * 64 + ct * 16 + li;
            float bs = bias[dblk + d_local];
#pragma unroll
            for (int rt = 0; rt < 4; ++rt) {
#pragma unroll
                for (int i = 0; i < 4; ++i) {
                    int n_local = rh * 64 + rt * 16 + q * 4 + i;
                    T[d_local][n_local] = f2bf(acc[rt][ct][i] + bs);
                }
            }
        }
        __syncthreads();
        int b = m0 >> 8, nbase = m0 & 255;
        int dl = tid >> 1;
        int nh = (tid & 1) * 64;
        int d = dblk + dl;
        int rr = d >> 6, dk = d & 63;
        unsigned short* dst = wvT + ((size_t)(b * NREL + rr) * DKK + dk) * NOBJ + nbase + nh;
#pragma unroll
        for (int k = 0; k < 8; ++k)
            *(bf16x8*)(dst + k * 8) = *(const bf16x8*)(&T[dl][nh + k * 8]);
    }
}

// ---------------- K5: flash attention, one block per (b,r), 256 rows, online softmax ----------------
// 4 waves x 64 rows; stream 8 col-tiles of 32; every global slice read exactly once.
// No __syncthreads: P round-trip LDS region is per-wave; row softmax state lives in
// the quad's 16 lanes (shfl_xor 1/2/4/8 reductions only).
__launch_bounds__(256)
__global__ void k_attn(const unsigned short* __restrict__ wg1, const unsigned short* __restrict__ wg2,
                       const unsigned short* __restrict__ wk, const unsigned short* __restrict__ wq,
                       const unsigned short* __restrict__ wvT,
                       const unsigned short* __restrict__ tmap, const float* __restrict__ v_mask,
                       const float* __restrict__ v, float* __restrict__ out) {
    int br = blockIdx.x;
    int b = br >> 3, r = br & 7;
    int tid = threadIdx.x;
    int w = tid >> 6, lane = tid & 63, q = lane >> 4, li = lane & 15;

    __shared__ __align__(16) unsigned short P_lds[4][64][36];

    // held A-fragments: wg1/wk rows (wave's 64 rows x 64 k)
    bf16x8 ag[4][2], ak[4][2];
    {
        const unsigned short* g1b = wg1 + (size_t)(b * NOBJ + w * 64 + li) * DIM + r * DKK + q * 8;
        const unsigned short* kb  = wk  + (size_t)(b * NOBJ + w * 64 + li) * DIM + r * DKK + q * 8;
#pragma unroll
        for (int rt = 0; rt < 4; ++rt)
#pragma unroll
            for (int kt = 0; kt < 2; ++kt) {
                ag[rt][kt] = *(const bf16x8*)(g1b + (size_t)rt * 16 * DIM + kt * 32);
                ak[rt][kt] = *(const bf16x8*)(kb + (size_t)rt * 16 * DIM + kt * 32);
            }
    }

    f32x4 O[4][4];
    float m_[4][4], l_[4][4];
#pragma unroll
    for (int rt = 0; rt < 4; ++rt) {
#pragma unroll
        for (int dt = 0; dt < 4; ++dt) O[rt][dt] = (f32x4){0.f, 0.f, 0.f, 0.f};
#pragma unroll
        for (int i = 0; i < 4; ++i) { m_[rt][i] = -INFINITY; l_[rt][i] = 0.f; }
    }

    const unsigned short* tb = tmap + ((size_t)b << 16) + (w * 64 + q * 4) * 256 + li;

    for (int j = 0; j < 8; ++j) {
        int c0 = j * 32;
        // B fragments: wg2/wq cols (32) x k (64)
        bf16x8 bg[2][2], bq[2][2];
        {
            const unsigned short* g2b = wg2 + (size_t)(b * NOBJ + c0 + li) * DIM + r * DKK + q * 8;
            const unsigned short* qb  = wq  + (size_t)(b * NOBJ + c0 + li) * DIM + r * DKK + q * 8;
#pragma unroll
            for (int ct = 0; ct < 2; ++ct)
#pragma unroll
                for (int kt = 0; kt < 2; ++kt) {
                    bg[ct][kt] = *(const bf16x8*)(g2b + (size_t)ct * 16 * DIM + kt * 32);
                    bq[ct][kt] = *(const bf16x8*)(qb + (size_t)ct * 16 * DIM + kt * 32);
                }
        }
        float vm0 = v_mask[b * NOBJ + c0 + li];
        float vm1 = v_mask[b * NOBJ + c0 + 16 + li];

        float s[4][2][4];
#pragma unroll
        for (int rt = 0; rt < 4; ++rt) {
#pragma unroll
            for (int ct = 0; ct < 2; ++ct) {
                f32x4 aG = (f32x4){0.f, 0.f, 0.f, 0.f};
                f32x4 aK = (f32x4){0.f, 0.f, 0.f, 0.f};
#pragma unroll
                for (int kt = 0; kt < 2; ++kt) {
                    aG = __builtin_amdgcn_mfma_f32_16x16x32_bf16(ag[rt][kt], bg[ct][kt], aG, 0, 0, 0);
                    aK = __builtin_amdgcn_mfma_f32_16x16x32_bf16(ak[rt][kt], bq[ct][kt], aK, 0, 0, 0);
                }
                float vm = ct ? vm1 : vm0;
#pragma unroll
                for (int i = 0; i < 4; ++i) {
                    float tm = bf2f(tb[(rt * 16 + i) * 256 + c0 + ct * 16]);
                    float g = fmaxf(aG[i], 0.f) + tm;
                    float sv = __logf(fmaxf(g, 1e-6f)) + aK[i] * 0.125f;
                    s[rt][ct][i] = (vm == 0.f) ? -INFINITY : sv;
                }
            }
        }
        // online softmax update + P write + PV
#pragma unroll
        for (int rt = 0; rt < 4; ++rt) {
            float alpha[4];
#pragma unroll
            for (int i = 0; i < 4; ++i) {
                float tmax = fmaxf(s[rt][0][i], s[rt][1][i]);
                tmax = fmaxf(tmax, __shfl_xor(tmax, 1));
                tmax = fmaxf(tmax, __shfl_xor(tmax, 2));
                tmax = fmaxf(tmax, __shfl_xor(tmax, 4));
                tmax = fmaxf(tmax, __shfl_xor(tmax, 8));
                float mo = m_[rt][i];
                float mn = fmaxf(mo, tmax);
                float al = (mo == -INFINITY) ? 0.f : __expf(mo - mn);
                m_[rt][i] = mn;
                alpha[i] = al;
                float p0 = __expf(s[rt][0][i] - mn);
                float p1 = __expf(s[rt][1][i] - mn);
                float ps = p0 + p1;
                ps += __shfl_xor(ps, 1);
                ps += __shfl_xor(ps, 2);
                ps += __shfl_xor(ps, 4);
                ps += __shfl_xor(ps, 8);
                l_[rt][i] = l_[rt][i] * al + ps;
                int row = rt * 16 + q * 4 + i;
                P_lds[w][row][li] = f2bf(p0);
                P_lds[w][row][16 + li] = f2bf(p1);
            }
#pragma unroll
            for (int dt = 0; dt < 4; ++dt) {
                f32x4 o = O[rt][dt];
                o[0] *= alpha[0]; o[1] *= alpha[1]; o[2] *= alpha[2]; o[3] *= alpha[3];
                O[rt][dt] = o;
            }
        }
        bf16x8 pa[4], vb[4];
#pragma unroll
        for (int rt = 0; rt < 4; ++rt)
            pa[rt] = *(const bf16x8*)(&P_lds[w][rt * 16 + li][q * 8]);
#pragma unroll
        for (int dt = 0; dt < 4; ++dt)
            vb[dt] = *(const bf16x8*)(wvT + (size_t)(br * DKK + dt * 16 + li) * NOBJ + c0 + q * 8);
#pragma unroll
        for (int rt = 0; rt < 4; ++rt)
#pragma unroll
            for (int dt = 0; dt < 4; ++dt)
                O[rt][dt] = __builtin_amdgcn_mfma_f32_16x16x32_bf16(pa[rt], vb[dt], O[rt][dt], 0, 0, 0);
    }

    // epilogue: O/l + residual
#pragma unroll
    for (int rt = 0; rt < 4; ++rt) {
        float linv[4];
#pragma unroll
        for (int i = 0; i < 4; ++i) linv[i] = 1.f / l_[rt][i];
#pragma unroll
        for (int dt = 0; dt < 4; ++dt) {
#pragma unroll
            for (int i = 0; i < 4; ++i) {
                int n = w * 64 + rt * 16 + q * 4 + i;
                size_t idx = (size_t)(b * NOBJ + n) * DIM + r * DKK + dt * 16 + li;
                out[idx] = O[rt][dt][i] * linv[i] + v[idx];
            }
        }
    }
}

extern "C" void kernel_launch(void* const* d_in, const int* in_sizes, int n_in,
                              void* d_out, int out_size, void* d_ws, size_t ws_size,
                              hipStream_t stream) {
    const float* v      = (const float*)d_in[0];
    const float* b      = (const float*)d_in[1];
    const float* v_mask = (const float*)d_in[2];
    const float* t      = (const float*)d_in[3];
    const float* t_mask = (const float*)d_in[4];
    const float* WG1_w  = (const float*)d_in[5];
    const float* WG1_b  = (const float*)d_in[6];
    const float* WG2_w  = (const float*)d_in[7];
    const float* WG2_b  = (const float*)d_in[8];
    const float* WK_w   = (const float*)d_in[9];
    const float* WK_b   = (const float*)d_in[10];
    const float* WQ_w   = (const float*)d_in[11];
    const float* WQ_b   = (const float*)d_in[12];
    const float* WV_w   = (const float*)d_in[13];
    const float* WV_b   = (const float*)d_in[14];
    const float* tc_w   = (const float*)d_in[15];
    const float* tc_b   = (const float*)d_in[16];
    const float* tmap_w = (const float*)d_in[17];
    const float* tmap_b = (const float*)d_in[18];
    float* out = (float*)d_out;

    char* ws = (char*)d_ws;
    size_t off = 0;
    auto alloc = [&](size_t bytes) {
        void* p = ws + off;
        off += (bytes + 255) & ~(size_t)255;
        return p;
    };
    unsigned short* ts_bf = (unsigned short*)alloc((size_t)BS * DIM * 2);
    unsigned short* tmap  = (unsigned short*)alloc((size_t)BS * NN * 2);
    unsigned short* v_bf  = (unsigned short*)alloc((size_t)BS * NOBJ * DIM * 2);
    unsigned short* b_bf  = (unsigned short*)alloc((size_t)BS * NOBJ * DIM * 2);
    unsigned short* WT    = (unsigned short*)alloc((size_t)5 * DIM * DIM * 2);
    unsigned short* wg1   = (unsigned short*)alloc((size_t)BS * NOBJ * DIM * 2);
    unsigned short* wg2   = (unsigned short*)alloc((size_t)BS * NOBJ * DIM * 2);
    unsigned short* wk    = (unsigned short*)alloc((size_t)BS * NOBJ * DIM * 2);
    unsigned short* wq    = (unsigned short*)alloc((size_t)BS * NOBJ * DIM * 2);
    unsigned short* wvT   = (unsigned short*)alloc((size_t)BS * NOBJ * DIM * 2);

    k_text<<<dim3(BS), dim3(256), 0, stream>>>(t, t_mask, tc_w, tc_b, ts_bf);
    k_convert<<<dim3(8192, 2), dim3(256), 0, stream>>>(v, b, v_bf, b_bf);
    k_wt<<<dim3(8, 8, 5), dim3(256), 0, stream>>>(WG1_w, WG2_w, WK_w, WQ_w, WV_w, WT);
    k_tmap<<<dim3(1024), dim3(64), 0, stream>>>(ts_bf, tmap_w, tmap_b, tmap);
    k_proj<<<dim3(128, 20), dim3(256), 0, stream>>>(v_bf, b_bf, WT,
                                                    WG1_b, WG2_b, WK_b, WQ_b, WV_b, v_mask,
                                                    wg1, wg2, wk, wq, wvT);
    k_attn<<<dim3(512), dim3(256), 0, stream>>>(wg1, wg2, wk, wq, wvT, tmap, v_mask, v, out);
}

// Round 4
// 471.148 us; speedup vs baseline: 1.2211x; 1.0494x over previous
//
#include <hip/hip_runtime.h>
#include <math.h>

#define BS 64
#define NOBJ 256
#define TTOK 32
#define DIM 512
#define NREL 8
#define DKK 64
#define NN 65536

typedef __attribute__((ext_vector_type(8))) short bf16x8;
typedef __attribute__((ext_vector_type(4))) float f32x4;

__device__ __forceinline__ unsigned short f2bf(float x) {
    union { float f; unsigned int u; } c; c.f = x;
    unsigned int u = c.u;
    return (unsigned short)((u + 0x7fffu + ((u >> 16) & 1u)) >> 16);
}
__device__ __forceinline__ float bf2f(unsigned short h) {
    union { unsigned int u; float f; } c; c.u = ((unsigned int)h) << 16;
    return c.f;
}
// async 16B global -> LDS (wave-uniform LDS base + lane*16)
__device__ __forceinline__ void gl2lds16(const unsigned short* g, unsigned short* l) {
    __builtin_amdgcn_global_load_lds((const __attribute__((address_space(1))) void*)g,
                                     (__attribute__((address_space(3))) void*)l, 16, 0, 0);
}

// ---------------- K1: text summary -> t_summary (bf16, 64x512) ----------------
__global__ void k_text(const float* __restrict__ tt, const float* __restrict__ t_mask,
                       const float* __restrict__ tc_w, const float* __restrict__ tc_b,
                       unsigned short* __restrict__ ts_bf) {
    int b = blockIdx.x;
    int tid = threadIdx.x;
    __shared__ float red[TTOK][8];
    __shared__ float sc[TTOK];
    {
        int tok = tid >> 3, seg = tid & 7;
        const float* tp = tt + (size_t)(b * TTOK + tok) * DIM + seg * 64;
        const float* wp = tc_w + seg * 64;
        float s = 0.f;
#pragma unroll
        for (int i = 0; i < 16; ++i) {
            float4 a = *(const float4*)(tp + i * 4);
            float4 w = *(const float4*)(wp + i * 4);
            s += a.x * w.x + a.y * w.y + a.z * w.z + a.w * w.w;
        }
        red[tok][seg] = s;
    }
    __syncthreads();
    if (tid < TTOK) {
        float s = 0.f;
#pragma unroll
        for (int i = 0; i < 8; ++i) s += red[tid][i];
        float m = t_mask[b * TTOK + tid];
        float tc = m * s + tc_b[0];
        float sig = 1.f / (1.f + __expf(-tc));
        sc[tid] = (m != 0.f) ? m * sig : 0.f;
    }
    __syncthreads();
    for (int d = tid; d < DIM; d += 256) {
        float acc = 0.f;
#pragma unroll
        for (int tok = 0; tok < TTOK; ++tok)
            acc += tt[(size_t)(b * TTOK + tok) * DIM + d] * sc[tok];
        ts_bf[b * DIM + d] = f2bf(acc);
    }
}

// ---------------- K3a: convert v,b to bf16 ----------------
__global__ void k_convert(const float* __restrict__ v, const float* __restrict__ b,
                          unsigned short* __restrict__ v_bf, unsigned short* __restrict__ b_bf) {
    const float* src = blockIdx.y ? b : v;
    unsigned short* dst = blockIdx.y ? b_bf : v_bf;
    size_t i = ((size_t)blockIdx.x * 256 + threadIdx.x) * 4;
    float4 a = *(const float4*)(src + i);
    ushort4 o;
    o.x = f2bf(a.x); o.y = f2bf(a.y); o.z = f2bf(a.z); o.w = f2bf(a.w);
    *(ushort4*)(dst + i) = o;
}

// ---------------- K3b: weights -> WT (2560 cols x 512 k, bf16, k-contiguous) ----------------
__global__ void k_wt(const float* __restrict__ w0, const float* __restrict__ w1,
                     const float* __restrict__ w2, const float* __restrict__ w3,
                     const float* __restrict__ w4, unsigned short* __restrict__ WT) {
    int wsel = blockIdx.z;
    const float* W = wsel == 0 ? w0 : wsel == 1 ? w1 : wsel == 2 ? w2 : wsel == 3 ? w3 : w4;
    int k0 = blockIdx.x * 64, d0 = blockIdx.y * 64;
    __shared__ float tile[64][65];
    int tid = threadIdx.x;
#pragma unroll
    for (int p = 0; p < 16; ++p) {
        int lin = p * 256 + tid;
        int kk = lin >> 6, dd = lin & 63;
        tile[kk][dd] = W[(size_t)(k0 + kk) * DIM + d0 + dd];
    }
    __syncthreads();
    unsigned short* outp = WT + (size_t)wsel * DIM * DIM;
#pragma unroll
    for (int p = 0; p < 16; ++p) {
        int lin = p * 256 + tid;
        int dd = lin >> 6, kk = lin & 63;
        outp[(size_t)(d0 + dd) * DIM + k0 + kk] = f2bf(tile[kk][dd]);
    }
}

// ---------------- K2: tmap = relu(ts @ tmap_w + tmap_b), (64 x 65536) -> bf16 ----------------
// R2 staged version: 1024 blocks x 256 threads, 64 cols/block; contiguous 256 B
// global reads per 64-lane group, LDS-staged B with pad-40 rows.
__launch_bounds__(256)
__global__ void k_tmap(const unsigned short* __restrict__ ts_bf,
                       const float* __restrict__ tmap_w, const float* __restrict__ tmap_b,
                       unsigned short* __restrict__ tmap) {
    int j0 = blockIdx.x * 64;
    int tid = threadIdx.x;
    int w = tid >> 6, lane = tid & 63, q = lane >> 4, li = lane & 15;
    __shared__ __align__(16) unsigned short Bt[64][40];
    f32x4 acc[4];
#pragma unroll
    for (int ct = 0; ct < 4; ++ct) acc[ct] = (f32x4){0.f, 0.f, 0.f, 0.f};

    for (int ks = 0; ks < 16; ++ks) {
        int k0 = ks * 32;
#pragma unroll
        for (int p = 0; p < 8; ++p) {
            int kk = (tid >> 6) + p * 4;
            int c = tid & 63;
            Bt[c][kk] = f2bf(tmap_w[(size_t)(k0 + kk) * NN + j0 + c]);
        }
        __syncthreads();
        bf16x8 a = *(const bf16x8*)(ts_bf + (size_t)(w * 16 + li) * DIM + k0 + q * 8);
#pragma unroll
        for (int ct = 0; ct < 4; ++ct) {
            bf16x8 bb = *(const bf16x8*)(&Bt[ct * 16 + li][q * 8]);
            acc[ct] = __builtin_amdgcn_mfma_f32_16x16x32_bf16(a, bb, acc[ct], 0, 0, 0);
        }
        __syncthreads();
    }
#pragma unroll
    for (int ct = 0; ct < 4; ++ct) {
        int j = j0 + ct * 16 + li;
        float bias = tmap_b[j];
#pragma unroll
        for (int i = 0; i < 4; ++i) {
            int bb = w * 16 + q * 4 + i;
            float val = fmaxf(acc[ct][i] + bias, 0.f);
            tmap[(size_t)bb * NN + j] = f2bf(val);
        }
    }
}

// ---------------- K4: 5 projections, BK=64, swizzled DMA staging, coalesced epilogue ----------
// LDS tile: 128 rows x 64 k shorts (128 B/row = 8 x 16B segments).
// Physical seg(row, logical s) = s ^ (row & 7). DMA lane l (1 KB/wave covering
// 8 rows): row_local = l>>3, phys seg = l&7 -> fetch logical (l&7)^(l>>3).
// Frag read (row = base16+li, segs j*4+q): phys = (j*4+q)^(li&7) -> 8 distinct
// segments per 8 lanes = conflict-free b128.
__launch_bounds__(256)
__global__ void k_proj(const unsigned short* __restrict__ v_bf, const unsigned short* __restrict__ b_bf,
                       const unsigned short* __restrict__ WT,
                       const float* __restrict__ bias0, const float* __restrict__ bias1,
                       const float* __restrict__ bias2, const float* __restrict__ bias3,
                       const float* __restrict__ bias4, const float* __restrict__ v_mask,
                       unsigned short* __restrict__ wg1, unsigned short* __restrict__ wg2,
                       unsigned short* __restrict__ wk, unsigned short* __restrict__ wq,
                       unsigned short* __restrict__ wvT) {
    int bx = blockIdx.x;          // 128 row blocks of 128
    int by = blockIdx.y;          // 20 col blocks of 128 (5 weights x 4)
    int m0 = bx * 128;
    int wsel = by >> 2;
    const unsigned short* A = (wsel < 2) ? b_bf : v_bf;
    int tid = threadIdx.x;
    int w = tid >> 6, lane = tid & 63, q = lane >> 4, li = lane & 15;
    int rh = w & 1, ch = w >> 1;

    __shared__ __align__(16) unsigned short smem[128 * 136];  // 34816 B; K-loop uses 32768
    unsigned short* As = smem;          // 8192 shorts
    unsigned short* Bs = smem + 8192;   // 8192 shorts

    f32x4 acc[4][4];
#pragma unroll
    for (int rt = 0; rt < 4; ++rt)
#pragma unroll
        for (int ct = 0; ct < 4; ++ct) acc[rt][ct] = (f32x4){0.f, 0.f, 0.f, 0.f};

    const unsigned short* WTb = WT + (size_t)by * 128 * DIM;

    // staging pointers: wave w covers chunks w*4..w*4+3 (8 rows each)
    int rl = lane >> 3;
    int lseg = (lane & 7) ^ rl;
    const unsigned short* Agp[4];
    const unsigned short* Bgp[4];
    unsigned short* Alp[4];
    unsigned short* Blp[4];
#pragma unroll
    for (int c4 = 0; c4 < 4; ++c4) {
        int c = w * 4 + c4;
        int row = c * 8 + rl;
        Agp[c4] = A + (size_t)(m0 + row) * DIM + lseg * 8;
        Bgp[c4] = WTb + (size_t)row * DIM + lseg * 8;
        Alp[c4] = As + c * 512;
        Blp[c4] = Bs + c * 512;
    }

    int arow = (rh * 64 + li) * 64;
    int brow = (ch * 64 + li) * 64;
    int sseg0 = ((q) ^ (li & 7)) * 8;
    int sseg1 = ((4 + q) ^ (li & 7)) * 8;

    for (int ks = 0; ks < 8; ++ks) {
        int k0 = ks * 64;
#pragma unroll
        for (int c4 = 0; c4 < 4; ++c4) {
            gl2lds16(Agp[c4] + k0, Alp[c4]);
            gl2lds16(Bgp[c4] + k0, Blp[c4]);
        }
        __syncthreads();
#pragma unroll
        for (int j = 0; j < 2; ++j) {
            int sseg = j ? sseg1 : sseg0;
            bf16x8 af[4], bfr[4];
#pragma unroll
            for (int rt = 0; rt < 4; ++rt)
                af[rt] = *(const bf16x8*)(As + arow + rt * 1024 + sseg);
#pragma unroll
            for (int ct = 0; ct < 4; ++ct)
                bfr[ct] = *(const bf16x8*)(Bs + brow + ct * 1024 + sseg);
#pragma unroll
            for (int rt = 0; rt < 4; ++rt)
#pragma unroll
                for (int ct = 0; ct < 4; ++ct)
                    acc[rt][ct] = __builtin_amdgcn_mfma_f32_16x16x32_bf16(af[rt], bfr[ct], acc[rt][ct], 0, 0, 0);
        }
        __syncthreads();
    }

    const float* bias = wsel == 0 ? bias0 : wsel == 1 ? bias1 : wsel == 2 ? bias2 : wsel == 3 ? bias3 : bias4;
    int dblk = (by & 3) * 128;

    // epilogue: LDS transit for coalesced 256 B-contiguous stores
    unsigned short (*T)[136] = (unsigned short (*)[136])smem;
    if (wsel < 4) {
        // T[n_local][d_local]
#pragma unroll
        for (int ct = 0; ct < 4; ++ct) {
            int d = dblk + ch * 64 + ct * 16 + li;
            float bs = bias[d];
#pragma unroll
            for (int rt = 0; rt < 4; ++rt) {
#pragma unroll
                for (int i = 0; i < 4; ++i) {
                    int nl = rh * 64 + rt * 16 + q * 4 + i;
                    float val = acc[rt][ct][i] + bs;
                    if (wsel < 2) val *= v_mask[m0 + nl];
                    T[nl][ch * 64 + ct * 16 + li] = f2bf(val);
                }
            }
        }
        __syncthreads();
        unsigned short* dstb = wsel == 0 ? wg1 : wsel == 1 ? wg2 : wsel == 2 ? wk : wq;
        int dc = lane & 15;
#pragma unroll
        for (int rr = 0; rr < 8; ++rr) {
            int outer = w * 32 + rr * 4 + (lane >> 4);
            *(bf16x8*)(dstb + (size_t)(m0 + outer) * DIM + dblk + dc * 8) =
                *(const bf16x8*)(&T[outer][dc * 8]);
        }
    } else {
        // T[d_local][n_local]
#pragma unroll
        for (int ct = 0; ct < 4; ++ct) {
            int dl = ch * 64 + ct * 16 + li;
            float bs = bias[dblk + dl];
#pragma unroll
            for (int rt = 0; rt < 4; ++rt) {
#pragma unroll
                for (int i = 0; i < 4; ++i) {
                    int nl = rh * 64 + rt * 16 + q * 4 + i;
                    T[dl][nl] = f2bf(acc[rt][ct][i] + bs);
                }
            }
        }
        __syncthreads();
        int b = m0 >> 8, nbase = m0 & 255;
        int dc = lane & 15;
#pragma unroll
        for (int rr = 0; rr < 8; ++rr) {
            int outer = w * 32 + rr * 4 + (lane >> 4);
            int d = dblk + outer;
            int r = d >> 6, dk = d & 63;
            *(bf16x8*)(wvT + ((size_t)(b * NREL + r) * DKK + dk) * NOBJ + nbase + dc * 8) =
                *(const bf16x8*)(&T[outer][dc * 8]);
        }
    }
}

// ---------------- K5: flash attention, one block per (b,r), 256 rows, online softmax ----------------
__launch_bounds__(256)
__global__ void k_attn(const unsigned short* __restrict__ wg1, const unsigned short* __restrict__ wg2,
                       const unsigned short* __restrict__ wk, const unsigned short* __restrict__ wq,
                       const unsigned short* __restrict__ wvT,
                       const unsigned short* __restrict__ tmap, const float* __restrict__ v_mask,
                       const float* __restrict__ v, float* __restrict__ out) {
    int br = blockIdx.x;
    int b = br >> 3, r = br & 7;
    int tid = threadIdx.x;
    int w = tid >> 6, lane = tid & 63, q = lane >> 4, li = lane & 15;

    __shared__ __align__(16) unsigned short P_lds[4][64][36];

    bf16x8 ag[4][2], ak[4][2];
    {
        const unsigned short* g1b = wg1 + (size_t)(b * NOBJ + w * 64 + li) * DIM + r * DKK + q * 8;
        const unsigned short* kb  = wk  + (size_t)(b * NOBJ + w * 64 + li) * DIM + r * DKK + q * 8;
#pragma unroll
        for (int rt = 0; rt < 4; ++rt)
#pragma unroll
            for (int kt = 0; kt < 2; ++kt) {
                ag[rt][kt] = *(const bf16x8*)(g1b + (size_t)rt * 16 * DIM + kt * 32);
                ak[rt][kt] = *(const bf16x8*)(kb + (size_t)rt * 16 * DIM + kt * 32);
            }
    }

    f32x4 O[4][4];
    float m_[4][4], l_[4][4];
#pragma unroll
    for (int rt = 0; rt < 4; ++rt) {
#pragma unroll
        for (int dt = 0; dt < 4; ++dt) O[rt][dt] = (f32x4){0.f, 0.f, 0.f, 0.f};
#pragma unroll
        for (int i = 0; i < 4; ++i) { m_[rt][i] = -INFINITY; l_[rt][i] = 0.f; }
    }

    const unsigned short* tb = tmap + ((size_t)b << 16) + (w * 64 + q * 4) * 256 + li;

    for (int j = 0; j < 8; ++j) {
        int c0 = j * 32;
        bf16x8 bg[2][2], bq[2][2];
        {
            const unsigned short* g2b = wg2 + (size_t)(b * NOBJ + c0 + li) * DIM + r * DKK + q * 8;
            const unsigned short* qb  = wq  + (size_t)(b * NOBJ + c0 + li) * DIM + r * DKK + q * 8;
#pragma unroll
            for (int ct = 0; ct < 2; ++ct)
#pragma unroll
                for (int kt = 0; kt < 2; ++kt) {
                    bg[ct][kt] = *(const bf16x8*)(g2b + (size_t)ct * 16 * DIM + kt * 32);
                    bq[ct][kt] = *(const bf16x8*)(qb + (size_t)ct * 16 * DIM + kt * 32);
                }
        }
        float vm0 = v_mask[b * NOBJ + c0 + li];
        float vm1 = v_mask[b * NOBJ + c0 + 16 + li];

        float s[4][2][4];
#pragma unroll
        for (int rt = 0; rt < 4; ++rt) {
#pragma unroll
            for (int ct = 0; ct < 2; ++ct) {
                f32x4 aG = (f32x4){0.f, 0.f, 0.f, 0.f};
                f32x4 aK = (f32x4){0.f, 0.f, 0.f, 0.f};
#pragma unroll
                for (int kt = 0; kt < 2; ++kt) {
                    aG = __builtin_amdgcn_mfma_f32_16x16x32_bf16(ag[rt][kt], bg[ct][kt], aG, 0, 0, 0);
                    aK = __builtin_amdgcn_mfma_f32_16x16x32_bf16(ak[rt][kt], bq[ct][kt], aK, 0, 0, 0);
                }
                float vm = ct ? vm1 : vm0;
#pragma unroll
                for (int i = 0; i < 4; ++i) {
                    float tm = bf2f(tb[(rt * 16 + i) * 256 + c0 + ct * 16]);
                    float g = fmaxf(aG[i], 0.f) + tm;
                    float sv = __logf(fmaxf(g, 1e-6f)) + aK[i] * 0.125f;
                    s[rt][ct][i] = (vm == 0.f) ? -INFINITY : sv;
                }
            }
        }
#pragma unroll
        for (int rt = 0; rt < 4; ++rt) {
            float alpha[4];
#pragma unroll
            for (int i = 0; i < 4; ++i) {
                float tmax = fmaxf(s[rt][0][i], s[rt][1][i]);
                tmax = fmaxf(tmax, __shfl_xor(tmax, 1));
                tmax = fmaxf(tmax, __shfl_xor(tmax, 2));
                tmax = fmaxf(tmax, __shfl_xor(tmax, 4));
                tmax = fmaxf(tmax, __shfl_xor(tmax, 8));
                float mo = m_[rt][i];
                float mn = fmaxf(mo, tmax);
                float al = (mo == -INFINITY) ? 0.f : __expf(mo - mn);
                m_[rt][i] = mn;
                alpha[i] = al;
                float p0 = __expf(s[rt][0][i] - mn);
                float p1 = __expf(s[rt][1][i] - mn);
                float ps = p0 + p1;
                ps += __shfl_xor(ps, 1);
                ps += __shfl_xor(ps, 2);
                ps += __shfl_xor(ps, 4);
                ps += __shfl_xor(ps, 8);
                l_[rt][i] = l_[rt][i] * al + ps;
                int row = rt * 16 + q * 4 + i;
                P_lds[w][row][li] = f2bf(p0);
                P_lds[w][row][16 + li] = f2bf(p1);
            }
#pragma unroll
            for (int dt = 0; dt < 4; ++dt) {
                f32x4 o = O[rt][dt];
                o[0] *= alpha[0]; o[1] *= alpha[1]; o[2] *= alpha[2]; o[3] *= alpha[3];
                O[rt][dt] = o;
            }
        }
        bf16x8 pa[4], vb[4];
#pragma unroll
        for (int rt = 0; rt < 4; ++rt)
            pa[rt] = *(const bf16x8*)(&P_lds[w][rt * 16 + li][q * 8]);
#pragma unroll
        for (int dt = 0; dt < 4; ++dt)
            vb[dt] = *(const bf16x8*)(wvT + (size_t)(br * DKK + dt * 16 + li) * NOBJ + c0 + q * 8);
#pragma unroll
        for (int rt = 0; rt < 4; ++rt)
#pragma unroll
            for (int dt = 0; dt < 4; ++dt)
                O[rt][dt] = __builtin_amdgcn_mfma_f32_16x16x32_bf16(pa[rt], vb[dt], O[rt][dt], 0, 0, 0);
    }

#pragma unroll
    for (int rt = 0; rt < 4; ++rt) {
        float linv[4];
#pragma unroll
        for (int i = 0; i < 4; ++i) linv[i] = 1.f / l_[rt][i];
#pragma unroll
        for (int dt = 0; dt < 4; ++dt) {
#pragma unroll
            for (int i = 0; i < 4; ++i) {
                int n = w * 64 + rt * 16 + q * 4 + i;
                size_t idx = (size_t)(b * NOBJ + n) * DIM + r * DKK + dt * 16 + li;
                out[idx] = O[rt][dt][i] * linv[i] + v[idx];
            }
        }
    }
}

extern "C" void kernel_launch(void* const* d_in, const int* in_sizes, int n_in,
                              void* d_out, int out_size, void* d_ws, size_t ws_size,
                              hipStream_t stream) {
    const float* v      = (const float*)d_in[0];
    const float* b      = (const float*)d_in[1];
    const float* v_mask = (const float*)d_in[2];
    const float* t      = (const float*)d_in[3];
    const float* t_mask = (const float*)d_in[4];
    const float* WG1_w  = (const float*)d_in[5];
    const float* WG1_b  = (const float*)d_in[6];
    const float* WG2_w  = (const float*)d_in[7];
    const float* WG2_b  = (const float*)d_in[8];
    const float* WK_w   = (const float*)d_in[9];
    const float* WK_b   = (const float*)d_in[10];
    const float* WQ_w   = (const float*)d_in[11];
    const float* WQ_b   = (const float*)d_in[12];
    const float* WV_w   = (const float*)d_in[13];
    const float* WV_b   = (const float*)d_in[14];
    const float* tc_w   = (const float*)d_in[15];
    const float* tc_b   = (const float*)d_in[16];
    const float* tmap_w = (const float*)d_in[17];
    const float* tmap_b = (const float*)d_in[18];
    float* out = (float*)d_out;

    char* ws = (char*)d_ws;
    size_t off = 0;
    auto alloc = [&](size_t bytes) {
        void* p = ws + off;
        off += (bytes + 255) & ~(size_t)255;
        return p;
    };
    unsigned short* ts_bf = (unsigned short*)alloc((size_t)BS * DIM * 2);
    unsigned short* tmap  = (unsigned short*)alloc((size_t)BS * NN * 2);
    unsigned short* v_bf  = (unsigned short*)alloc((size_t)BS * NOBJ * DIM * 2);
    unsigned short* b_bf  = (unsigned short*)alloc((size_t)BS * NOBJ * DIM * 2);
    unsigned short* WT    = (unsigned short*)alloc((size_t)5 * DIM * DIM * 2);
    unsigned short* wg1   = (unsigned short*)alloc((size_t)BS * NOBJ * DIM * 2);
    unsigned short* wg2   = (unsigned short*)alloc((size_t)BS * NOBJ * DIM * 2);
    unsigned short* wk    = (unsigned short*)alloc((size_t)BS * NOBJ * DIM * 2);
    unsigned short* wq    = (unsigned short*)alloc((size_t)BS * NOBJ * DIM * 2);
    unsigned short* wvT   = (unsigned short*)alloc((size_t)BS * NOBJ * DIM * 2);

    k_text<<<dim3(BS), dim3(256), 0, stream>>>(t, t_mask, tc_w, tc_b, ts_bf);
    k_convert<<<dim3(8192, 2), dim3(256), 0, stream>>>(v, b, v_bf, b_bf);
    k_wt<<<dim3(8, 8, 5), dim3(256), 0, stream>>>(WG1_w, WG2_w, WK_w, WQ_w, WV_w, WT);
    k_tmap<<<dim3(1024), dim3(256), 0, stream>>>(ts_bf, tmap_w, tmap_b, tmap);
    k_proj<<<dim3(128, 20), dim3(256), 0, stream>>>(v_bf, b_bf, WT,
                                                    WG1_b, WG2_b, WK_b, WQ_b, WV_b, v_mask,
                                                    wg1, wg2, wk, wq, wvT);
    k_attn<<<dim3(512), dim3(256), 0, stream>>>(wg1, wg2, wk, wq, wvT, tmap, v_mask, v, out);
}

// Round 5
// 461.863 us; speedup vs baseline: 1.2457x; 1.0201x over previous
//
#include <hip/hip_runtime.h>
#include <math.h>

#define BS 64
#define NOBJ 256
#define TTOK 32
#define DIM 512
#define NREL 8
#define DKK 64
#define NN 65536

typedef __attribute__((ext_vector_type(8))) short bf16x8;
typedef __attribute__((ext_vector_type(4))) float f32x4;

__device__ __forceinline__ unsigned short f2bf(float x) {
    union { float f; unsigned int u; } c; c.f = x;
    unsigned int u = c.u;
    return (unsigned short)((u + 0x7fffu + ((u >> 16) & 1u)) >> 16);
}
__device__ __forceinline__ float bf2f(unsigned short h) {
    union { unsigned int u; float f; } c; c.u = ((unsigned int)h) << 16;
    return c.f;
}
// async 16B global -> LDS (wave-uniform LDS base + lane*16)
__device__ __forceinline__ void gl2lds16(const unsigned short* g, unsigned short* l) {
    __builtin_amdgcn_global_load_lds((const __attribute__((address_space(1))) void*)g,
                                     (__attribute__((address_space(3))) void*)l, 16, 0, 0);
}

// ---------------- K1: text summary -> t_summary (bf16, 64x512) ----------------
__global__ void k_text(const float* __restrict__ tt, const float* __restrict__ t_mask,
                       const float* __restrict__ tc_w, const float* __restrict__ tc_b,
                       unsigned short* __restrict__ ts_bf) {
    int b = blockIdx.x;
    int tid = threadIdx.x;
    __shared__ float red[TTOK][8];
    __shared__ float sc[TTOK];
    {
        int tok = tid >> 3, seg = tid & 7;
        const float* tp = tt + (size_t)(b * TTOK + tok) * DIM + seg * 64;
        const float* wp = tc_w + seg * 64;
        float s = 0.f;
#pragma unroll
        for (int i = 0; i < 16; ++i) {
            float4 a = *(const float4*)(tp + i * 4);
            float4 w = *(const float4*)(wp + i * 4);
            s += a.x * w.x + a.y * w.y + a.z * w.z + a.w * w.w;
        }
        red[tok][seg] = s;
    }
    __syncthreads();
    if (tid < TTOK) {
        float s = 0.f;
#pragma unroll
        for (int i = 0; i < 8; ++i) s += red[tid][i];
        float m = t_mask[b * TTOK + tid];
        float tc = m * s + tc_b[0];
        float sig = 1.f / (1.f + __expf(-tc));
        sc[tid] = (m != 0.f) ? m * sig : 0.f;
    }
    __syncthreads();
    for (int d = tid; d < DIM; d += 256) {
        float acc = 0.f;
#pragma unroll
        for (int tok = 0; tok < TTOK; ++tok)
            acc += tt[(size_t)(b * TTOK + tok) * DIM + d] * sc[tok];
        ts_bf[b * DIM + d] = f2bf(acc);
    }
}

// ---------------- K3a: convert v,b to bf16 ----------------
__global__ void k_convert(const float* __restrict__ v, const float* __restrict__ b,
                          unsigned short* __restrict__ v_bf, unsigned short* __restrict__ b_bf) {
    const float* src = blockIdx.y ? b : v;
    unsigned short* dst = blockIdx.y ? b_bf : v_bf;
    size_t i = ((size_t)blockIdx.x * 256 + threadIdx.x) * 4;
    float4 a = *(const float4*)(src + i);
    ushort4 o;
    o.x = f2bf(a.x); o.y = f2bf(a.y); o.z = f2bf(a.z); o.w = f2bf(a.w);
    *(ushort4*)(dst + i) = o;
}

// ---------------- K3b: weights -> WT (2560 cols x 512 k, bf16, k-contiguous) ----------------
__global__ void k_wt(const float* __restrict__ w0, const float* __restrict__ w1,
                     const float* __restrict__ w2, const float* __restrict__ w3,
                     const float* __restrict__ w4, unsigned short* __restrict__ WT) {
    int wsel = blockIdx.z;
    const float* W = wsel == 0 ? w0 : wsel == 1 ? w1 : wsel == 2 ? w2 : wsel == 3 ? w3 : w4;
    int k0 = blockIdx.x * 64, d0 = blockIdx.y * 64;
    __shared__ float tile[64][65];
    int tid = threadIdx.x;
#pragma unroll
    for (int p = 0; p < 16; ++p) {
        int lin = p * 256 + tid;
        int kk = lin >> 6, dd = lin & 63;
        tile[kk][dd] = W[(size_t)(k0 + kk) * DIM + d0 + dd];
    }
    __syncthreads();
    unsigned short* outp = WT + (size_t)wsel * DIM * DIM;
#pragma unroll
    for (int p = 0; p < 16; ++p) {
        int lin = p * 256 + tid;
        int dd = lin >> 6, kk = lin & 63;
        outp[(size_t)(d0 + dd) * DIM + k0 + kk] = f2bf(tile[kk][dd]);
    }
}

// ---------------- K2: tmap = relu(ts @ tmap_w + tmap_b), (64 x 65536) -> bf16 ----------------
__launch_bounds__(256)
__global__ void k_tmap(const unsigned short* __restrict__ ts_bf,
                       const float* __restrict__ tmap_w, const float* __restrict__ tmap_b,
                       unsigned short* __restrict__ tmap) {
    int j0 = blockIdx.x * 64;
    int tid = threadIdx.x;
    int w = tid >> 6, lane = tid & 63, q = lane >> 4, li = lane & 15;
    __shared__ __align__(16) unsigned short Bt[64][40];
    f32x4 acc[4];
#pragma unroll
    for (int ct = 0; ct < 4; ++ct) acc[ct] = (f32x4){0.f, 0.f, 0.f, 0.f};

    for (int ks = 0; ks < 16; ++ks) {
        int k0 = ks * 32;
#pragma unroll
        for (int p = 0; p < 8; ++p) {
            int kk = (tid >> 6) + p * 4;
            int c = tid & 63;
            Bt[c][kk] = f2bf(tmap_w[(size_t)(k0 + kk) * NN + j0 + c]);
        }
        __syncthreads();
        bf16x8 a = *(const bf16x8*)(ts_bf + (size_t)(w * 16 + li) * DIM + k0 + q * 8);
#pragma unroll
        for (int ct = 0; ct < 4; ++ct) {
            bf16x8 bb = *(const bf16x8*)(&Bt[ct * 16 + li][q * 8]);
            acc[ct] = __builtin_amdgcn_mfma_f32_16x16x32_bf16(a, bb, acc[ct], 0, 0, 0);
        }
        __syncthreads();
    }
#pragma unroll
    for (int ct = 0; ct < 4; ++ct) {
        int j = j0 + ct * 16 + li;
        float bias = tmap_b[j];
#pragma unroll
        for (int i = 0; i < 4; ++i) {
            int bb = w * 16 + q * 4 + i;
            float val = fmaxf(acc[ct][i] + bias, 0.f);
            tmap[(size_t)bb * NN + j] = f2bf(val);
        }
    }
}

// ---------------- K4: 5 projections, BK=64, swizzled DMA staging, coalesced epilogue ----------
__launch_bounds__(256)
__global__ void k_proj(const unsigned short* __restrict__ v_bf, const unsigned short* __restrict__ b_bf,
                       const unsigned short* __restrict__ WT,
                       const float* __restrict__ bias0, const float* __restrict__ bias1,
                       const float* __restrict__ bias2, const float* __restrict__ bias3,
                       const float* __restrict__ bias4, const float* __restrict__ v_mask,
                       unsigned short* __restrict__ wg1, unsigned short* __restrict__ wg2,
                       unsigned short* __restrict__ wk, unsigned short* __restrict__ wq,
                       unsigned short* __restrict__ wvT) {
    int bx = blockIdx.x;
    int by = blockIdx.y;
    int m0 = bx * 128;
    int wsel = by >> 2;
    const unsigned short* A = (wsel < 2) ? b_bf : v_bf;
    int tid = threadIdx.x;
    int w = tid >> 6, lane = tid & 63, q = lane >> 4, li = lane & 15;
    int rh = w & 1, ch = w >> 1;

    __shared__ __align__(16) unsigned short smem[128 * 136];
    unsigned short* As = smem;
    unsigned short* Bs = smem + 8192;

    f32x4 acc[4][4];
#pragma unroll
    for (int rt = 0; rt < 4; ++rt)
#pragma unroll
        for (int ct = 0; ct < 4; ++ct) acc[rt][ct] = (f32x4){0.f, 0.f, 0.f, 0.f};

    const unsigned short* WTb = WT + (size_t)by * 128 * DIM;

    int rl = lane >> 3;
    int lseg = (lane & 7) ^ rl;
    const unsigned short* Agp[4];
    const unsigned short* Bgp[4];
    unsigned short* Alp[4];
    unsigned short* Blp[4];
#pragma unroll
    for (int c4 = 0; c4 < 4; ++c4) {
        int c = w * 4 + c4;
        int row = c * 8 + rl;
        Agp[c4] = A + (size_t)(m0 + row) * DIM + lseg * 8;
        Bgp[c4] = WTb + (size_t)row * DIM + lseg * 8;
        Alp[c4] = As + c * 512;
        Blp[c4] = Bs + c * 512;
    }

    int arow = (rh * 64 + li) * 64;
    int brow = (ch * 64 + li) * 64;
    int sseg0 = ((q) ^ (li & 7)) * 8;
    int sseg1 = ((4 + q) ^ (li & 7)) * 8;

    for (int ks = 0; ks < 8; ++ks) {
        int k0 = ks * 64;
#pragma unroll
        for (int c4 = 0; c4 < 4; ++c4) {
            gl2lds16(Agp[c4] + k0, Alp[c4]);
            gl2lds16(Bgp[c4] + k0, Blp[c4]);
        }
        __syncthreads();
#pragma unroll
        for (int j = 0; j < 2; ++j) {
            int sseg = j ? sseg1 : sseg0;
            bf16x8 af[4], bfr[4];
#pragma unroll
            for (int rt = 0; rt < 4; ++rt)
                af[rt] = *(const bf16x8*)(As + arow + rt * 1024 + sseg);
#pragma unroll
            for (int ct = 0; ct < 4; ++ct)
                bfr[ct] = *(const bf16x8*)(Bs + brow + ct * 1024 + sseg);
#pragma unroll
            for (int rt = 0; rt < 4; ++rt)
#pragma unroll
                for (int ct = 0; ct < 4; ++ct)
                    acc[rt][ct] = __builtin_amdgcn_mfma_f32_16x16x32_bf16(af[rt], bfr[ct], acc[rt][ct], 0, 0, 0);
        }
        __syncthreads();
    }

    const float* bias = wsel == 0 ? bias0 : wsel == 1 ? bias1 : wsel == 2 ? bias2 : wsel == 3 ? bias3 : bias4;
    int dblk = (by & 3) * 128;

    unsigned short (*T)[136] = (unsigned short (*)[136])smem;
    if (wsel < 4) {
#pragma unroll
        for (int ct = 0; ct < 4; ++ct) {
            int d = dblk + ch * 64 + ct * 16 + li;
            float bs = bias[d];
#pragma unroll
            for (int rt = 0; rt < 4; ++rt) {
#pragma unroll
                for (int i = 0; i < 4; ++i) {
                    int nl = rh * 64 + rt * 16 + q * 4 + i;
                    float val = acc[rt][ct][i] + bs;
                    if (wsel < 2) val *= v_mask[m0 + nl];
                    T[nl][ch * 64 + ct * 16 + li] = f2bf(val);
                }
            }
        }
        __syncthreads();
        unsigned short* dstb = wsel == 0 ? wg1 : wsel == 1 ? wg2 : wsel == 2 ? wk : wq;
        int dc = lane & 15;
#pragma unroll
        for (int rr = 0; rr < 8; ++rr) {
            int outer = w * 32 + rr * 4 + (lane >> 4);
            *(bf16x8*)(dstb + (size_t)(m0 + outer) * DIM + dblk + dc * 8) =
                *(const bf16x8*)(&T[outer][dc * 8]);
        }
    } else {
#pragma unroll
        for (int ct = 0; ct < 4; ++ct) {
            int dl = ch * 64 + ct * 16 + li;
            float bs = bias[dblk + dl];
#pragma unroll
            for (int rt = 0; rt < 4; ++rt) {
#pragma unroll
                for (int i = 0; i < 4; ++i) {
                    int nl = rh * 64 + rt * 16 + q * 4 + i;
                    T[dl][nl] = f2bf(acc[rt][ct][i] + bs);
                }
            }
        }
        __syncthreads();
        int b = m0 >> 8, nbase = m0 & 255;
        int dc = lane & 15;
#pragma unroll
        for (int rr = 0; rr < 8; ++rr) {
            int outer = w * 32 + rr * 4 + (lane >> 4);
            int d = dblk + outer;
            int r = d >> 6, dk = d & 63;
            *(bf16x8*)(wvT + ((size_t)(b * NREL + r) * DKK + dk) * NOBJ + nbase + dc * 8) =
                *(const bf16x8*)(&T[outer][dc * 8]);
        }
    }
}

// ---------------- K5: attention, p = g_clamped * exp(dot/8) identity (no log, no online max) ----
// Grid 1024: XCD-swizzled decode; block = (b, r, rowhalf of 128). 4 waves x 32 rows.
// No shuffles in the j-loop; l is a per-lane partial reduced once at the end.
__launch_bounds__(256)
__global__ void k_attn(const unsigned short* __restrict__ wg1, const unsigned short* __restrict__ wg2,
                       const unsigned short* __restrict__ wk, const unsigned short* __restrict__ wq,
                       const unsigned short* __restrict__ wvT,
                       const unsigned short* __restrict__ tmap, const float* __restrict__ v_mask,
                       const float* __restrict__ v, float* __restrict__ out) {
    int L = blockIdx.x;
    int x = L & 7, jj = L >> 3;
    int b = x + 8 * (jj >> 4);           // same-b blocks share launch-id mod 8 (XCD locality)
    int inner = jj & 15;
    int r = inner >> 1, half = inner & 1;
    int br = b * NREL + r;

    int tid = threadIdx.x;
    int w = tid >> 6, lane = tid & 63, q = lane >> 4, li = lane & 15;
    int n0 = half * 128 + w * 32;        // wave's 32 rows

    __shared__ __align__(16) unsigned short P_lds[4][32][36];

    // A-fragments: wg1/wk rows (32 x 64k)
    bf16x8 ag[2][2], ak[2][2];
    {
        const unsigned short* g1b = wg1 + (size_t)(b * NOBJ + n0 + li) * DIM + r * DKK + q * 8;
        const unsigned short* kb  = wk  + (size_t)(b * NOBJ + n0 + li) * DIM + r * DKK + q * 8;
#pragma unroll
        for (int rt = 0; rt < 2; ++rt)
#pragma unroll
            for (int kt = 0; kt < 2; ++kt) {
                ag[rt][kt] = *(const bf16x8*)(g1b + (size_t)rt * 16 * DIM + kt * 32);
                ak[rt][kt] = *(const bf16x8*)(kb + (size_t)rt * 16 * DIM + kt * 32);
            }
    }

    f32x4 O[2][4];
    float lsum[2][4];
#pragma unroll
    for (int rt = 0; rt < 2; ++rt) {
#pragma unroll
        for (int dt = 0; dt < 4; ++dt) O[rt][dt] = (f32x4){0.f, 0.f, 0.f, 0.f};
#pragma unroll
        for (int i = 0; i < 4; ++i) lsum[rt][i] = 0.f;
    }

    const unsigned short* tb = tmap + ((size_t)b << 16) + (n0 + q * 4) * 256 + li;

    for (int j = 0; j < 8; ++j) {
        int c0 = j * 32;
        bf16x8 bg[2][2], bq[2][2];
        {
            const unsigned short* g2b = wg2 + (size_t)(b * NOBJ + c0 + li) * DIM + r * DKK + q * 8;
            const unsigned short* qb  = wq  + (size_t)(b * NOBJ + c0 + li) * DIM + r * DKK + q * 8;
#pragma unroll
            for (int ct = 0; ct < 2; ++ct)
#pragma unroll
                for (int kt = 0; kt < 2; ++kt) {
                    bg[ct][kt] = *(const bf16x8*)(g2b + (size_t)ct * 16 * DIM + kt * 32);
                    bq[ct][kt] = *(const bf16x8*)(qb + (size_t)ct * 16 * DIM + kt * 32);
                }
        }
        float vm0 = v_mask[b * NOBJ + c0 + li];
        float vm1 = v_mask[b * NOBJ + c0 + 16 + li];

#pragma unroll
        for (int rt = 0; rt < 2; ++rt) {
#pragma unroll
            for (int ct = 0; ct < 2; ++ct) {
                f32x4 aG = (f32x4){0.f, 0.f, 0.f, 0.f};
                f32x4 aK = (f32x4){0.f, 0.f, 0.f, 0.f};
#pragma unroll
                for (int kt = 0; kt < 2; ++kt) {
                    aG = __builtin_amdgcn_mfma_f32_16x16x32_bf16(ag[rt][kt], bg[ct][kt], aG, 0, 0, 0);
                    aK = __builtin_amdgcn_mfma_f32_16x16x32_bf16(ak[rt][kt], bq[ct][kt], aK, 0, 0, 0);
                }
                float vm = ct ? vm1 : vm0;
#pragma unroll
                for (int i = 0; i < 4; ++i) {
                    // p = max(relu(G)+tmap, 1e-6) * exp(dot/8); exact softmax after /l.
                    float tm = bf2f(tb[(rt * 16 + i) * 256 + c0 + ct * 16]);
                    float g = fmaxf(fmaxf(aG[i], 0.f) + tm, 1e-6f);
                    float p = (vm == 0.f) ? 0.f : g * __expf(aK[i] * 0.125f);
                    lsum[rt][i] += p;
                    P_lds[w][rt * 16 + q * 4 + i][ct * 16 + li] = f2bf(p);
                }
            }
        }
        bf16x8 pa[2], vb[4];
#pragma unroll
        for (int rt = 0; rt < 2; ++rt)
            pa[rt] = *(const bf16x8*)(&P_lds[w][rt * 16 + li][q * 8]);
#pragma unroll
        for (int dt = 0; dt < 4; ++dt)
            vb[dt] = *(const bf16x8*)(wvT + (size_t)(br * DKK + dt * 16 + li) * NOBJ + c0 + q * 8);
#pragma unroll
        for (int rt = 0; rt < 2; ++rt)
#pragma unroll
            for (int dt = 0; dt < 4; ++dt)
                O[rt][dt] = __builtin_amdgcn_mfma_f32_16x16x32_bf16(pa[rt], vb[dt], O[rt][dt], 0, 0, 0);
    }

    // epilogue: reduce l over the 16 li lanes, then out = O/l + v
#pragma unroll
    for (int rt = 0; rt < 2; ++rt) {
        float linv[4];
#pragma unroll
        for (int i = 0; i < 4; ++i) {
            float s = lsum[rt][i];
            s += __shfl_xor(s, 1);
            s += __shfl_xor(s, 2);
            s += __shfl_xor(s, 4);
            s += __shfl_xor(s, 8);
            linv[i] = 1.f / s;
        }
#pragma unroll
        for (int dt = 0; dt < 4; ++dt) {
#pragma unroll
            for (int i = 0; i < 4; ++i) {
                int n = n0 + rt * 16 + q * 4 + i;
                size_t idx = (size_t)(b * NOBJ + n) * DIM + r * DKK + dt * 16 + li;
                out[idx] = O[rt][dt][i] * linv[i] + v[idx];
            }
        }
    }
}

extern "C" void kernel_launch(void* const* d_in, const int* in_sizes, int n_in,
                              void* d_out, int out_size, void* d_ws, size_t ws_size,
                              hipStream_t stream) {
    const float* v      = (const float*)d_in[0];
    const float* b      = (const float*)d_in[1];
    const float* v_mask = (const float*)d_in[2];
    const float* t      = (const float*)d_in[3];
    const float* t_mask = (const float*)d_in[4];
    const float* WG1_w  = (const float*)d_in[5];
    const float* WG1_b  = (const float*)d_in[6];
    const float* WG2_w  = (const float*)d_in[7];
    const float* WG2_b  = (const float*)d_in[8];
    const float* WK_w   = (const float*)d_in[9];
    const float* WK_b   = (const float*)d_in[10];
    const float* WQ_w   = (const float*)d_in[11];
    const float* WQ_b   = (const float*)d_in[12];
    const float* WV_w   = (const float*)d_in[13];
    const float* WV_b   = (const float*)d_in[14];
    const float* tc_w   = (const float*)d_in[15];
    const float* tc_b   = (const float*)d_in[16];
    const float* tmap_w = (const float*)d_in[17];
    const float* tmap_b = (const float*)d_in[18];
    float* out = (float*)d_out;

    char* ws = (char*)d_ws;
    size_t off = 0;
    auto alloc = [&](size_t bytes) {
        void* p = ws + off;
        off += (bytes + 255) & ~(size_t)255;
        return p;
    };
    unsigned short* ts_bf = (unsigned short*)alloc((size_t)BS * DIM * 2);
    unsigned short* tmap  = (unsigned short*)alloc((size_t)BS * NN * 2);
    unsigned short* v_bf  = (unsigned short*)alloc((size_t)BS * NOBJ * DIM * 2);
    unsigned short* b_bf  = (unsigned short*)alloc((size_t)BS * NOBJ * DIM * 2);
    unsigned short* WT    = (unsigned short*)alloc((size_t)5 * DIM * DIM * 2);
    unsigned short* wg1   = (unsigned short*)alloc((size_t)BS * NOBJ * DIM * 2);
    unsigned short* wg2   = (unsigned short*)alloc((size_t)BS * NOBJ * DIM * 2);
    unsigned short* wk    = (unsigned short*)alloc((size_t)BS * NOBJ * DIM * 2);
    unsigned short* wq    = (unsigned short*)alloc((size_t)BS * NOBJ * DIM * 2);
    unsigned short* wvT   = (unsigned short*)alloc((size_t)BS * NOBJ * DIM * 2);

    k_text<<<dim3(BS), dim3(256), 0, stream>>>(t, t_mask, tc_w, tc_b, ts_bf);
    k_convert<<<dim3(8192, 2), dim3(256), 0, stream>>>(v, b, v_bf, b_bf);
    k_wt<<<dim3(8, 8, 5), dim3(256), 0, stream>>>(WG1_w, WG2_w, WK_w, WQ_w, WV_w, WT);
    k_tmap<<<dim3(1024), dim3(256), 0, stream>>>(ts_bf, tmap_w, tmap_b, tmap);
    k_proj<<<dim3(128, 20), dim3(256), 0, stream>>>(v_bf, b_bf, WT,
                                                    WG1_b, WG2_b, WK_b, WQ_b, WV_b, v_mask,
                                                    wg1, wg2, wk, wq, wvT);
    k_attn<<<dim3(1024), dim3(256), 0, stream>>>(wg1, wg2, wk, wq, wvT, tmap, v_mask, v, out);
}